// Round 2
// baseline (489.041 us; speedup 1.0000x reference)
//
#include <hip/hip_runtime.h>
#include <stdint.h>

typedef __attribute__((ext_vector_type(8))) short short8;
typedef __attribute__((ext_vector_type(4))) float f32x4;
typedef unsigned int u32;
typedef unsigned short u16;

#define T_TOK 2048
#define DMODEL 768
#define DFF 2048
#define NEXP 8
#define NROWS 4096  // T_TOK * TOP_K

#define BKP 40      // padded k-extent (elems) of transposed W tiles in LDS
#define WSTR 20     // uint (2-elem) stride per n-column

// meta int layout in ws: [0..7]=cnt [8..15]=cur [16..24]=off [25]=isbf16 flag
#define M_CNT 0
#define M_CUR 8
#define M_OFF 16
#define M_FLAG 25

__device__ __forceinline__ float b2f(u16 u) {
  union { u32 i; float f; } v; v.i = ((u32)u) << 16; return v.f;
}
__device__ __forceinline__ u16 f2b(float f) {
  union { float f; u32 i; } v; v.f = f;
  return (u16)((v.i + 0x7fffu + ((v.i >> 16) & 1u)) >> 16);
}
__device__ __forceinline__ u32 pack2(float lo, float hi) {
  return (u32)f2b(lo) | ((u32)f2b(hi) << 16);
}
__device__ __forceinline__ uint4 cvt8(float4 a, float4 b) {
  uint4 r; r.x = pack2(a.x, a.y); r.y = pack2(a.z, a.w);
  r.z = pack2(b.x, b.y); r.w = pack2(b.z, b.w); return r;
}

// ---------------- detect dtype + init ----------------
// Reads first 4096 u16 of x. bf16 N(0,1) data: exponent field <= 129 always.
// fp32 data read as u16 halves: low halves have ~uniform exponent -> ~37% >= 160.
__global__ void k_detect(const u16* __restrict__ x, int* __restrict__ meta,
                         void* __restrict__ outv) {
  int lane = threadIdx.x;  // 64 threads
  int susp = 0;
  for (int i = 0; i < 64; ++i) {
    u16 v = x[lane + (i << 6)];
    int ex = (v >> 7) & 0xFF;
    susp += (ex >= 160) ? 1 : 0;
  }
#pragma unroll
  for (int s = 32; s >= 1; s >>= 1) susp += __shfl_xor(susp, s);
  if (lane < NEXP) meta[M_CNT + lane] = 0;
  if (lane == 0) {
    int isbf = (susp <= 32) ? 1 : 0;
    meta[M_FLAG] = isbf;
    // loss output = 0.0 at flat index T_TOK*DMODEL, dtype per flag
    if (isbf) ((u16*)outv)[(size_t)T_TOK * DMODEL] = 0;
    else      ((float*)outv)[(size_t)T_TOK * DMODEL] = 0.f;
  }
}

// ---------------- router: one wave per token ----------------
template <int ISBF>
__global__ __launch_bounds__(256) void k_router(
    const void* __restrict__ xv, const void* __restrict__ gwv,
    int* __restrict__ meta, int* __restrict__ t2e, float* __restrict__ t2w) {
  if (meta[M_FLAG] != ISBF) return;
  int lane = threadIdx.x & 63;
  int t = blockIdx.x * 4 + (threadIdx.x >> 6);
  float acc[8];
#pragma unroll
  for (int e = 0; e < 8; ++e) acc[e] = 0.f;
  if (ISBF) {
    const u16* xr = (const u16*)xv + (size_t)t * DMODEL;
    const u16* gw = (const u16*)gwv;
#pragma unroll
    for (int i = 0; i < 12; ++i) {
      int d = lane + (i << 6);
      float xd = b2f(xr[d]);
      uint4 g = *(const uint4*)(gw + d * 8);
      acc[0] += xd * b2f((u16)(g.x & 0xffffu));
      acc[1] += xd * b2f((u16)(g.x >> 16));
      acc[2] += xd * b2f((u16)(g.y & 0xffffu));
      acc[3] += xd * b2f((u16)(g.y >> 16));
      acc[4] += xd * b2f((u16)(g.z & 0xffffu));
      acc[5] += xd * b2f((u16)(g.z >> 16));
      acc[6] += xd * b2f((u16)(g.w & 0xffffu));
      acc[7] += xd * b2f((u16)(g.w >> 16));
    }
  } else {
    const float* xr = (const float*)xv + (size_t)t * DMODEL;
    const float* gw = (const float*)gwv;
#pragma unroll
    for (int i = 0; i < 12; ++i) {
      int d = lane + (i << 6);
      float xd = xr[d];
      float4 g0 = *(const float4*)(gw + d * 8);
      float4 g1 = *(const float4*)(gw + d * 8 + 4);
      acc[0] += xd * g0.x; acc[1] += xd * g0.y;
      acc[2] += xd * g0.z; acc[3] += xd * g0.w;
      acc[4] += xd * g1.x; acc[5] += xd * g1.y;
      acc[6] += xd * g1.z; acc[7] += xd * g1.w;
    }
  }
#pragma unroll
  for (int s = 32; s >= 1; s >>= 1) {
#pragma unroll
    for (int e = 0; e < 8; ++e) acc[e] += __shfl_xor(acc[e], s);
  }
  if (lane == 0) {
    int i0 = 0;
#pragma unroll
    for (int e = 1; e < 8; ++e) if (acc[e] > acc[i0]) i0 = e;
    int i1 = (i0 == 0) ? 1 : 0;
#pragma unroll
    for (int e = 0; e < 8; ++e) if (e != i0 && acc[e] > acc[i1]) i1 = e;
    float w0 = 1.f / (1.f + __expf(acc[i1] - acc[i0]));
    t2e[2 * t] = i0; t2e[2 * t + 1] = i1;
    t2w[2 * t] = w0; t2w[2 * t + 1] = 1.f - w0;
    atomicAdd(&meta[M_CNT + i0], 1); atomicAdd(&meta[M_CNT + i1], 1);
  }
}

// ---------------- exclusive scan of 8 counts ----------------
__global__ void k_scan(int* __restrict__ meta) {
  if (threadIdx.x == 0) {
    int r = 0;
    for (int e = 0; e < NEXP; ++e) {
      meta[M_OFF + e] = r; meta[M_CUR + e] = r; r += meta[M_CNT + e];
    }
    meta[M_OFF + NEXP] = r;
  }
}

// ---------------- scatter tokens into expert buckets ----------------
__global__ __launch_bounds__(256) void k_scatter(
    const int* __restrict__ t2e, int* __restrict__ meta,
    int* __restrict__ tok_of_row, int* __restrict__ slot_of) {
  int t = blockIdx.x * 256 + threadIdx.x;
#pragma unroll
  for (int k = 0; k < 2; ++k) {
    int e = t2e[2 * t + k];
    int r = atomicAdd(&meta[M_CUR + e], 1);
    tok_of_row[r] = t;
    slot_of[2 * t + k] = r;
  }
}

// transpose-stage one 32x128 W tile (2 k-rows per thread) into [n][k] LDS layout
__device__ __forceinline__ void wpack(u32* lds, int k2, int n8, uint4 a, uint4 b) {
  int idx = n8 * WSTR + k2;
  lds[idx + 0 * WSTR] = (a.x & 0xffffu) | (b.x << 16);
  lds[idx + 1 * WSTR] = (a.x >> 16) | (b.x & 0xffff0000u);
  lds[idx + 2 * WSTR] = (a.y & 0xffffu) | (b.y << 16);
  lds[idx + 3 * WSTR] = (a.y >> 16) | (b.y & 0xffff0000u);
  lds[idx + 4 * WSTR] = (a.z & 0xffffu) | (b.z << 16);
  lds[idx + 5 * WSTR] = (a.z >> 16) | (b.z & 0xffff0000u);
  lds[idx + 6 * WSTR] = (a.w & 0xffffu) | (b.w << 16);
  lds[idx + 7 * WSTR] = (a.w >> 16) | (b.w & 0xffff0000u);
}

// ---------------- stage 1: X @ [Wg|Wu] -> H = silu(g)*u  (per expert) ----------------
template <int ISBF>
__global__ __launch_bounds__(256) void k_stage1(
    const void* __restrict__ xv, const void* __restrict__ wgv, const void* __restrict__ wuv,
    const int* __restrict__ meta, const int* __restrict__ tok, u16* __restrict__ H) {
  if (meta[M_FLAG] != ISBF) return;
  __shared__ u16 Xs[64 * 32];
  __shared__ u16 Wgs[128 * BKP];
  __shared__ u16 Wus[128 * BKP];
  int e = blockIdx.z;
  int off_e = meta[M_OFF + e];
  int rows_e = meta[M_OFF + e + 1] - off_e;
  int r0 = blockIdx.y * 64;
  if (r0 >= rows_e) return;
  int rows_t = rows_e - r0; if (rows_t > 64) rows_t = 64;
  int f0 = blockIdx.x * 128;
  int tid = threadIdx.x, lane = tid & 63, w = tid >> 6;
  int wr = w >> 1, wc = w & 1;

  int srow = (w << 4) + (lane >> 2);
  int trow = (srow < rows_t) ? tok[off_e + r0 + srow] : tok[off_e];
  int xcol = (lane & 3) << 3;
  u16* xl = &Xs[srow * 32 + xcol];

  int k2 = tid >> 4, n8 = (tid & 15) << 3;
  size_t wbase = (size_t)e * (DMODEL * DFF) + (size_t)(k2 << 1) * DFF + f0 + n8;

  f32x4 accg[2][4], accu[2][4];
#pragma unroll
  for (int i = 0; i < 2; ++i)
#pragma unroll
    for (int j = 0; j < 4; ++j) {
      accg[i][j] = (f32x4){0.f, 0.f, 0.f, 0.f};
      accu[i][j] = (f32x4){0.f, 0.f, 0.f, 0.f};
    }

  for (int kk = 0; kk < DMODEL / 32; ++kk) {
    int k0 = kk << 5;
    uint4 xa, ga, gb, ua, ub;
    if (ISBF) {
      const u16* xg = (const u16*)xv + (size_t)trow * DMODEL + xcol;
      const u16* wgp = (const u16*)wgv + wbase;
      const u16* wup = (const u16*)wuv + wbase;
      xa = *(const uint4*)(xg + k0);
      ga = *(const uint4*)(wgp + (size_t)k0 * DFF);
      gb = *(const uint4*)(wgp + (size_t)k0 * DFF + DFF);
      ua = *(const uint4*)(wup + (size_t)k0 * DFF);
      ub = *(const uint4*)(wup + (size_t)k0 * DFF + DFF);
    } else {
      const float* xg = (const float*)xv + (size_t)trow * DMODEL + xcol;
      const float* wgp = (const float*)wgv + wbase;
      const float* wup = (const float*)wuv + wbase;
      xa = cvt8(*(const float4*)(xg + k0), *(const float4*)(xg + k0 + 4));
      ga = cvt8(*(const float4*)(wgp + (size_t)k0 * DFF), *(const float4*)(wgp + (size_t)k0 * DFF + 4));
      gb = cvt8(*(const float4*)(wgp + (size_t)k0 * DFF + DFF), *(const float4*)(wgp + (size_t)k0 * DFF + DFF + 4));
      ua = cvt8(*(const float4*)(wup + (size_t)k0 * DFF), *(const float4*)(wup + (size_t)k0 * DFF + 4));
      ub = cvt8(*(const float4*)(wup + (size_t)k0 * DFF + DFF), *(const float4*)(wup + (size_t)k0 * DFF + DFF + 4));
    }
    __syncthreads();
    *(uint4*)xl = xa;
    wpack((u32*)Wgs, k2, n8, ga, gb);
    wpack((u32*)Wus, k2, n8, ua, ub);
    __syncthreads();
    short8 af[2];
#pragma unroll
    for (int mt = 0; mt < 2; ++mt)
      af[mt] = *(const short8*)&Xs[((wr << 5) + (mt << 4) + (lane & 15)) * 32 + ((lane >> 4) << 3)];
#pragma unroll
    for (int nt = 0; nt < 4; ++nt) {
      int col = (wc << 6) + (nt << 4) + (lane & 15);
      short8 bg = *(const short8*)&Wgs[col * BKP + ((lane >> 4) << 3)];
      short8 bu = *(const short8*)&Wus[col * BKP + ((lane >> 4) << 3)];
#pragma unroll
      for (int mt = 0; mt < 2; ++mt) {
        accg[mt][nt] = __builtin_amdgcn_mfma_f32_16x16x32_bf16(af[mt], bg, accg[mt][nt], 0, 0, 0);
        accu[mt][nt] = __builtin_amdgcn_mfma_f32_16x16x32_bf16(af[mt], bu, accu[mt][nt], 0, 0, 0);
      }
    }
  }
  int q = lane >> 4, c = lane & 15;
#pragma unroll
  for (int mt = 0; mt < 2; ++mt)
#pragma unroll
    for (int r = 0; r < 4; ++r) {
      int lrow = (wr << 5) + (mt << 4) + (q << 2) + r;
      if (lrow < rows_t) {
        size_t rowbase = (size_t)(off_e + r0 + lrow) * DFF + f0 + (wc << 6);
#pragma unroll
        for (int nt = 0; nt < 4; ++nt) {
          float g = accg[mt][nt][r], u = accu[mt][nt][r];
          float h = g / (1.f + __expf(-g)) * u;  // silu(g)*u
          H[rowbase + (nt << 4) + c] = f2b(h);
        }
      }
    }
}

// ---------------- stage 2: H @ Wd -> Opair (fp32) ----------------
template <int ISBF>
__global__ __launch_bounds__(256) void k_stage2(
    const u16* __restrict__ H, const void* __restrict__ wdv,
    const int* __restrict__ meta, float* __restrict__ Op) {
  if (meta[M_FLAG] != ISBF) return;
  __shared__ u16 As[64 * 32];
  __shared__ u16 Ws[128 * BKP];
  int e = blockIdx.z;
  int off_e = meta[M_OFF + e];
  int rows_e = meta[M_OFF + e + 1] - off_e;
  int r0 = blockIdx.y * 64;
  if (r0 >= rows_e) return;
  int rows_t = rows_e - r0; if (rows_t > 64) rows_t = 64;
  int n0 = blockIdx.x * 128;
  int tid = threadIdx.x, lane = tid & 63, w = tid >> 6;
  int wr = w >> 1, wc = w & 1;

  int srow = (w << 4) + (lane >> 2);
  int hrow = off_e + r0 + ((srow < rows_t) ? srow : 0);  // clamp: no OOB H reads
  const u16* ag = H + (size_t)hrow * DFF + ((lane & 3) << 3);
  u16* al = &As[srow * 32 + ((lane & 3) << 3)];

  int k2 = tid >> 4, n8 = (tid & 15) << 3;
  size_t wbase = (size_t)e * (DFF * DMODEL) + (size_t)(k2 << 1) * DMODEL + n0 + n8;

  f32x4 acc[2][4];
#pragma unroll
  for (int i = 0; i < 2; ++i)
#pragma unroll
    for (int j = 0; j < 4; ++j) acc[i][j] = (f32x4){0.f, 0.f, 0.f, 0.f};

  for (int kk = 0; kk < DFF / 32; ++kk) {
    int k0 = kk << 5;
    uint4 xa, ga, gb;
    xa = *(const uint4*)(ag + k0);
    if (ISBF) {
      const u16* wdp = (const u16*)wdv + wbase;
      ga = *(const uint4*)(wdp + (size_t)k0 * DMODEL);
      gb = *(const uint4*)(wdp + (size_t)k0 * DMODEL + DMODEL);
    } else {
      const float* wdp = (const float*)wdv + wbase;
      ga = cvt8(*(const float4*)(wdp + (size_t)k0 * DMODEL), *(const float4*)(wdp + (size_t)k0 * DMODEL + 4));
      gb = cvt8(*(const float4*)(wdp + (size_t)k0 * DMODEL + DMODEL), *(const float4*)(wdp + (size_t)k0 * DMODEL + DMODEL + 4));
    }
    __syncthreads();
    *(uint4*)al = xa;
    wpack((u32*)Ws, k2, n8, ga, gb);
    __syncthreads();
    short8 af[2];
#pragma unroll
    for (int mt = 0; mt < 2; ++mt)
      af[mt] = *(const short8*)&As[((wr << 5) + (mt << 4) + (lane & 15)) * 32 + ((lane >> 4) << 3)];
#pragma unroll
    for (int nt = 0; nt < 4; ++nt) {
      int col = (wc << 6) + (nt << 4) + (lane & 15);
      short8 b = *(const short8*)&Ws[col * BKP + ((lane >> 4) << 3)];
#pragma unroll
      for (int mt = 0; mt < 2; ++mt)
        acc[mt][nt] = __builtin_amdgcn_mfma_f32_16x16x32_bf16(af[mt], b, acc[mt][nt], 0, 0, 0);
    }
  }
  int q = lane >> 4, c = lane & 15;
#pragma unroll
  for (int mt = 0; mt < 2; ++mt)
#pragma unroll
    for (int r = 0; r < 4; ++r) {
      int lrow = (wr << 5) + (mt << 4) + (q << 2) + r;
      if (lrow < rows_t) {
        size_t rowbase = (size_t)(off_e + r0 + lrow) * DMODEL + n0 + (wc << 6);
#pragma unroll
        for (int nt = 0; nt < 4; ++nt)
          Op[rowbase + (nt << 4) + c] = acc[mt][nt][r];
      }
    }
}

// ---------------- combine: out[t] = w0*Op[slot0] + w1*Op[slot1] ----------------
template <int ISBF>
__global__ __launch_bounds__(192) void k_combine(
    const float* __restrict__ Op, const int* __restrict__ slot_of,
    const float* __restrict__ t2w, const int* __restrict__ meta, void* __restrict__ outv) {
  if (meta[M_FLAG] != ISBF) return;
  int t = blockIdx.x;
  int d4 = threadIdx.x << 2;
  int s0 = slot_of[2 * t], s1 = slot_of[2 * t + 1];
  float w0 = t2w[2 * t], w1 = t2w[2 * t + 1];
  float4 a = *(const float4*)&Op[(size_t)s0 * DMODEL + d4];
  float4 b = *(const float4*)&Op[(size_t)s1 * DMODEL + d4];
  float rx = w0 * a.x + w1 * b.x;
  float ry = w0 * a.y + w1 * b.y;
  float rz = w0 * a.z + w1 * b.z;
  float rw = w0 * a.w + w1 * b.w;
  if (ISBF) {
    ushort4 r; r.x = f2b(rx); r.y = f2b(ry); r.z = f2b(rz); r.w = f2b(rw);
    *(ushort4*)&((u16*)outv)[(size_t)t * DMODEL + d4] = r;
  } else {
    float4 r; r.x = rx; r.y = ry; r.z = rz; r.w = rw;
    *(float4*)&((float*)outv)[(size_t)t * DMODEL + d4] = r;
  }
}

extern "C" void kernel_launch(void* const* d_in, const int* in_sizes, int n_in,
                              void* d_out, int out_size, void* d_ws, size_t ws_size,
                              hipStream_t stream) {
  const void* x  = d_in[0];
  const void* gw = d_in[1];
  const void* wg = d_in[2];
  const void* wu = d_in[3];
  const void* wd = d_in[4];

  char* ws = (char*)d_ws;
  int* meta = (int*)ws;                                     // 256 B
  int* t2e        = (int*)(ws + 256);                       // [4096]
  int* slot_of    = (int*)(ws + 256 + 16384);               // [4096]
  int* tok_of_row = (int*)(ws + 256 + 32768);               // [4096]
  float* t2w      = (float*)(ws + 256 + 49152);             // [4096]
  u16* H          = (u16*)(ws + 65792);                     // [4096 * 2048] bf16 (16 MB)
  float* Opair    = (float*)(ws + 65792 + 16777216);        // [4096 * 768] fp32 (12.6 MB)

  k_detect<<<1, 64, 0, stream>>>((const u16*)x, meta, d_out);
  k_router<1><<<T_TOK / 4, 256, 0, stream>>>(x, gw, meta, t2e, t2w);
  k_router<0><<<T_TOK / 4, 256, 0, stream>>>(x, gw, meta, t2e, t2w);
  k_scan<<<1, 64, 0, stream>>>(meta);
  k_scatter<<<T_TOK / 256, 256, 0, stream>>>(t2e, meta, tok_of_row, slot_of);
  dim3 g1(DFF / 128, T_TOK / 64, NEXP);
  k_stage1<1><<<g1, 256, 0, stream>>>(x, wg, wu, meta, tok_of_row, H);
  k_stage1<0><<<g1, 256, 0, stream>>>(x, wg, wu, meta, tok_of_row, H);
  dim3 g2(DMODEL / 128, T_TOK / 64, NEXP);
  k_stage2<1><<<g2, 256, 0, stream>>>(H, wd, meta, Opair);
  k_stage2<0><<<g2, 256, 0, stream>>>(H, wd, meta, Opair);
  k_combine<1><<<T_TOK, 192, 0, stream>>>(Opair, slot_of, t2w, meta, d_out);
  k_combine<0><<<T_TOK, 192, 0, stream>>>(Opair, slot_of, t2w, meta, d_out);
}

// Round 4
// 438.638 us; speedup vs baseline: 1.1149x; 1.1149x over previous
//
#include <hip/hip_runtime.h>
#include <stdint.h>

typedef __attribute__((ext_vector_type(8))) short short8;
typedef __attribute__((ext_vector_type(4))) float f32x4;
typedef unsigned int u32;
typedef unsigned short u16;

#define T_TOK 2048
#define DMODEL 768
#define DFF 2048
#define NEXP 8

#define BKP 40      // padded LDS row stride (elems): 20 u32 -> 2-way max bank alias (free)
#define WSTR 20     // (fallback wpack) uint stride per n-column

// meta ints: [0..7]=cnt [8..15]=cur [16..24]=off
#define M_CNT 0
#define M_CUR 8
#define M_OFF 16

__device__ __forceinline__ float b2f(u16 u) {
  union { u32 i; float f; } v; v.i = ((u32)u) << 16; return v.f;
}
__device__ __forceinline__ u16 f2b(float f) {
  union { float f; u32 i; } v; v.f = f;
  return (u16)((v.i + 0x7fffu + ((v.i >> 16) & 1u)) >> 16);
}
__device__ __forceinline__ u32 pack2(float lo, float hi) {
  return (u32)f2b(lo) | ((u32)f2b(hi) << 16);
}
__device__ __forceinline__ uint4 cvt8(float4 a, float4 b) {
  uint4 r; r.x = pack2(a.x, a.y); r.y = pack2(a.z, a.w);
  r.z = pack2(b.x, b.y); r.w = pack2(b.z, b.w); return r;
}

// ---------------- init ----------------
__global__ void k_init(int* __restrict__ meta) {
  if (threadIdx.x < NEXP) meta[M_CNT + threadIdx.x] = 0;
}

// ---------------- router: one wave per token (fp32 in) ----------------
__global__ __launch_bounds__(256) void k_router(
    const float* __restrict__ x, const float* __restrict__ gw,
    int* __restrict__ meta, int* __restrict__ t2e, float* __restrict__ t2w) {
  int lane = threadIdx.x & 63;
  int t = blockIdx.x * 4 + (threadIdx.x >> 6);
  const float* xr = x + (size_t)t * DMODEL;
  float acc[8];
#pragma unroll
  for (int e = 0; e < 8; ++e) acc[e] = 0.f;
#pragma unroll
  for (int i = 0; i < 12; ++i) {
    int d = lane + (i << 6);
    float xd = xr[d];
    float4 g0 = *(const float4*)(gw + d * 8);
    float4 g1 = *(const float4*)(gw + d * 8 + 4);
    acc[0] += xd * g0.x; acc[1] += xd * g0.y;
    acc[2] += xd * g0.z; acc[3] += xd * g0.w;
    acc[4] += xd * g1.x; acc[5] += xd * g1.y;
    acc[6] += xd * g1.z; acc[7] += xd * g1.w;
  }
#pragma unroll
  for (int s = 32; s >= 1; s >>= 1) {
#pragma unroll
    for (int e = 0; e < 8; ++e) acc[e] += __shfl_xor(acc[e], s);
  }
  if (lane == 0) {
    int i0 = 0;
#pragma unroll
    for (int e = 1; e < 8; ++e) if (acc[e] > acc[i0]) i0 = e;
    int i1 = (i0 == 0) ? 1 : 0;
#pragma unroll
    for (int e = 0; e < 8; ++e) if (e != i0 && acc[e] > acc[i1]) i1 = e;
    float w0 = 1.f / (1.f + __expf(acc[i1] - acc[i0]));
    t2e[2 * t] = i0; t2e[2 * t + 1] = i1;
    t2w[2 * t] = w0; t2w[2 * t + 1] = 1.f - w0;
    atomicAdd(&meta[M_CNT + i0], 1); atomicAdd(&meta[M_CNT + i1], 1);
  }
}

// ---------------- exclusive scan of 8 counts + loss=0 ----------------
__global__ void k_scan(int* __restrict__ meta, float* __restrict__ outp) {
  if (threadIdx.x == 0) {
    int r = 0;
    for (int e = 0; e < NEXP; ++e) {
      meta[M_OFF + e] = r; meta[M_CUR + e] = r; r += meta[M_CNT + e];
    }
    meta[M_OFF + NEXP] = r;
    outp[(size_t)T_TOK * DMODEL] = 0.f;  // load_balancing_loss
  }
}

// ---------------- scatter tokens into expert buckets ----------------
__global__ __launch_bounds__(256) void k_scatter(
    const int* __restrict__ t2e, int* __restrict__ meta,
    int* __restrict__ tok_of_row, int* __restrict__ slot_of) {
  int t = blockIdx.x * 256 + threadIdx.x;
#pragma unroll
  for (int k = 0; k < 2; ++k) {
    int e = t2e[2 * t + k];
    int r = atomicAdd(&meta[M_CUR + e], 1);
    tok_of_row[r] = t;
    slot_of[2 * t + k] = r;
  }
}

// ---------------- pre-pass: x fp32 -> bf16 ----------------
__global__ __launch_bounds__(256) void k_xcvt(const float* __restrict__ x, u16* __restrict__ xb) {
  size_t i = ((size_t)blockIdx.x * 256 + threadIdx.x) * 8;
  float4 a = *(const float4*)(x + i);
  float4 b = *(const float4*)(x + i + 4);
  *(uint4*)(xb + i) = cvt8(a, b);
}

// ---------------- pre-pass: W [e][K][N] fp32 -> blocked bf16 [e][N/128][K/32][128][32]
__global__ __launch_bounds__(256) void k_wtrans(
    const float* __restrict__ in, u16* __restrict__ out, int K, int N) {
  __shared__ float T[32][136];
  int e = blockIdx.z, nx = blockIdx.x, ky = blockIdx.y;
  int t = threadIdx.x;
  const float* ip = in + (size_t)e * K * N + (size_t)(ky * 32) * N + nx * 128;
  int kr = t >> 3, nc = (t & 7) * 16;
  const float* rp = ip + (size_t)kr * N + nc;
  float4 v0 = *(const float4*)(rp);
  float4 v1 = *(const float4*)(rp + 4);
  float4 v2 = *(const float4*)(rp + 8);
  float4 v3 = *(const float4*)(rp + 12);
  *(float4*)&T[kr][nc] = v0;
  *(float4*)&T[kr][nc + 4] = v1;
  *(float4*)&T[kr][nc + 8] = v2;
  *(float4*)&T[kr][nc + 12] = v3;
  __syncthreads();
  int nr = t >> 1, kh = (t & 1) * 16;
  float v[16];
#pragma unroll
  for (int j = 0; j < 16; ++j) v[j] = T[kh + j][nr];
  uint4 o0, o1;
  o0.x = pack2(v[0], v[1]);  o0.y = pack2(v[2], v[3]);
  o0.z = pack2(v[4], v[5]);  o0.w = pack2(v[6], v[7]);
  o1.x = pack2(v[8], v[9]);  o1.y = pack2(v[10], v[11]);
  o1.z = pack2(v[12], v[13]); o1.w = pack2(v[14], v[15]);
  int NB = N >> 7, KB = K >> 5;
  u16* op = out + ((size_t)(e * NB + nx) * KB + ky) * 4096 + nr * 32 + kh;
  *(uint4*)op = o0;
  *(uint4*)(op + 8) = o1;
}

// ---------------- stage 1 (fast): Xb @ [WgB|WuB] -> H = silu(g)*u ----------------
// tile 128 rows x 128 cols, BK=32, 4 waves 2x2, wave tile 64x64
__global__ __launch_bounds__(256, 2) void k_stage1b(
    const u16* __restrict__ Xb, const u16* __restrict__ WgB, const u16* __restrict__ WuB,
    const int* __restrict__ meta, const int* __restrict__ tok, u16* __restrict__ H) {
  __shared__ u16 Xs[128 * BKP];
  __shared__ u16 Wgs[128 * BKP];
  __shared__ u16 Wus[128 * BKP];
  int e = blockIdx.z, fb = blockIdx.y;
  int off_e = meta[M_OFF + e];
  int rows_e = meta[M_OFF + e + 1] - off_e;
  int r0 = blockIdx.x * 128;
  if (r0 >= rows_e) return;
  int rows_t = rows_e - r0; if (rows_t > 128) rows_t = 128;
  int f0 = fb * 128;
  int tid = threadIdx.x, lane = tid & 63, w = tid >> 6;
  int wr = w >> 1, wc = w & 1, q = lane >> 4, lm = lane & 15;

  // A staging: 2 threads per row, 16 elems each
  int arow = tid >> 1, akh = (tid & 1) * 16;
  int trow = (arow < rows_t) ? tok[off_e + r0 + arow] : tok[off_e];
  const u16* xg = Xb + (size_t)trow * DMODEL + akh;
  u16* al = &Xs[arow * BKP + akh];
  // B staging: thread copies 16 contiguous elems of the 8KB chunk
  int bn = tid >> 1, bkh = (tid & 1) * 16;
  size_t chunk0 = (size_t)((e * 16 + fb) * 24) * 4096 + tid * 16;
  const u16* gsrc = WgB + chunk0;
  const u16* usrc = WuB + chunk0;
  u16* gl = &Wgs[bn * BKP + bkh];
  u16* ul = &Wus[bn * BKP + bkh];

  const u16* ap[4]; const u16* gp[4]; const u16* up[4];
#pragma unroll
  for (int mt = 0; mt < 4; ++mt) ap[mt] = &Xs[(wr * 64 + mt * 16 + lm) * BKP + q * 8];
#pragma unroll
  for (int nt = 0; nt < 4; ++nt) {
    gp[nt] = &Wgs[(wc * 64 + nt * 16 + lm) * BKP + q * 8];
    up[nt] = &Wus[(wc * 64 + nt * 16 + lm) * BKP + q * 8];
  }

  f32x4 accg[4][4], accu[4][4];
#pragma unroll
  for (int i = 0; i < 4; ++i)
#pragma unroll
    for (int j = 0; j < 4; ++j) {
      accg[i][j] = (f32x4){0.f, 0.f, 0.f, 0.f};
      accu[i][j] = (f32x4){0.f, 0.f, 0.f, 0.f};
    }

  for (int kk = 0; kk < DMODEL / 32; ++kk) {
    int k0 = kk << 5;
    uint4 a0 = *(const uint4*)(xg + k0);
    uint4 a1 = *(const uint4*)(xg + k0 + 8);
    uint4 g0 = *(const uint4*)(gsrc + (size_t)kk * 4096);
    uint4 g1 = *(const uint4*)(gsrc + (size_t)kk * 4096 + 8);
    uint4 u0 = *(const uint4*)(usrc + (size_t)kk * 4096);
    uint4 u1 = *(const uint4*)(usrc + (size_t)kk * 4096 + 8);
    __syncthreads();
    *(uint4*)al = a0; *(uint4*)(al + 8) = a1;
    *(uint4*)gl = g0; *(uint4*)(gl + 8) = g1;
    *(uint4*)ul = u0; *(uint4*)(ul + 8) = u1;
    __syncthreads();
    short8 af[4];
#pragma unroll
    for (int mt = 0; mt < 4; ++mt) af[mt] = *(const short8*)ap[mt];
#pragma unroll
    for (int nt = 0; nt < 4; ++nt) {
      short8 bg = *(const short8*)gp[nt];
      short8 bu = *(const short8*)up[nt];
#pragma unroll
      for (int mt = 0; mt < 4; ++mt) {
        accg[mt][nt] = __builtin_amdgcn_mfma_f32_16x16x32_bf16(af[mt], bg, accg[mt][nt], 0, 0, 0);
        accu[mt][nt] = __builtin_amdgcn_mfma_f32_16x16x32_bf16(af[mt], bu, accu[mt][nt], 0, 0, 0);
      }
    }
  }
#pragma unroll
  for (int mt = 0; mt < 4; ++mt)
#pragma unroll
    for (int r = 0; r < 4; ++r) {
      int lrow = wr * 64 + mt * 16 + q * 4 + r;
      if (lrow < rows_t) {
        size_t rowbase = (size_t)(off_e + r0 + lrow) * DFF + f0 + wc * 64;
#pragma unroll
        for (int nt = 0; nt < 4; ++nt) {
          float g = accg[mt][nt][r], u = accu[mt][nt][r];
          float h = g / (1.f + __expf(-g)) * u;
          H[rowbase + nt * 16 + lm] = f2b(h);
        }
      }
    }
}

// ---------------- stage 2 (fast): H @ WdB -> Op fp32 ----------------
__global__ __launch_bounds__(256, 2) void k_stage2b(
    const u16* __restrict__ H, const u16* __restrict__ WdB,
    const int* __restrict__ meta, float* __restrict__ Op) {
  __shared__ u16 As[128 * BKP];
  __shared__ u16 Ws[128 * BKP];
  int e = blockIdx.z, nb = blockIdx.y;
  int off_e = meta[M_OFF + e];
  int rows_e = meta[M_OFF + e + 1] - off_e;
  int r0 = blockIdx.x * 128;
  if (r0 >= rows_e) return;
  int rows_t = rows_e - r0; if (rows_t > 128) rows_t = 128;
  int n0 = nb * 128;
  int tid = threadIdx.x, lane = tid & 63, w = tid >> 6;
  int wr = w >> 1, wc = w & 1, q = lane >> 4, lm = lane & 15;

  int arow = tid >> 1, akh = (tid & 1) * 16;
  int hrow = off_e + r0 + ((arow < rows_t) ? arow : 0);
  const u16* ag = H + (size_t)hrow * DFF + akh;
  u16* al = &As[arow * BKP + akh];
  size_t chunk0 = (size_t)((e * 6 + nb) * 64) * 4096 + tid * 16;
  const u16* wsrc = WdB + chunk0;
  int bn = tid >> 1, bkh = (tid & 1) * 16;
  u16* wl = &Ws[bn * BKP + bkh];

  const u16* ap[4]; const u16* bp[4];
#pragma unroll
  for (int mt = 0; mt < 4; ++mt) ap[mt] = &As[(wr * 64 + mt * 16 + lm) * BKP + q * 8];
#pragma unroll
  for (int nt = 0; nt < 4; ++nt) bp[nt] = &Ws[(wc * 64 + nt * 16 + lm) * BKP + q * 8];

  f32x4 acc[4][4];
#pragma unroll
  for (int i = 0; i < 4; ++i)
#pragma unroll
    for (int j = 0; j < 4; ++j) acc[i][j] = (f32x4){0.f, 0.f, 0.f, 0.f};

  for (int kk = 0; kk < DFF / 32; ++kk) {
    int k0 = kk << 5;
    uint4 a0 = *(const uint4*)(ag + k0);
    uint4 a1 = *(const uint4*)(ag + k0 + 8);
    uint4 b0 = *(const uint4*)(wsrc + (size_t)kk * 4096);
    uint4 b1 = *(const uint4*)(wsrc + (size_t)kk * 4096 + 8);
    __syncthreads();
    *(uint4*)al = a0; *(uint4*)(al + 8) = a1;
    *(uint4*)wl = b0; *(uint4*)(wl + 8) = b1;
    __syncthreads();
    short8 af[4];
#pragma unroll
    for (int mt = 0; mt < 4; ++mt) af[mt] = *(const short8*)ap[mt];
#pragma unroll
    for (int nt = 0; nt < 4; ++nt) {
      short8 b = *(const short8*)bp[nt];
#pragma unroll
      for (int mt = 0; mt < 4; ++mt)
        acc[mt][nt] = __builtin_amdgcn_mfma_f32_16x16x32_bf16(af[mt], b, acc[mt][nt], 0, 0, 0);
    }
  }
#pragma unroll
  for (int mt = 0; mt < 4; ++mt)
#pragma unroll
    for (int r = 0; r < 4; ++r) {
      int lrow = wr * 64 + mt * 16 + q * 4 + r;
      if (lrow < rows_t) {
        size_t rowbase = (size_t)(off_e + r0 + lrow) * DMODEL + n0 + wc * 64;
#pragma unroll
        for (int nt = 0; nt < 4; ++nt)
          Op[rowbase + nt * 16 + lm] = acc[mt][nt][r];
      }
    }
}

// ---------------- combine: out[t] = w0*Op[slot0] + w1*Op[slot1] (fp32 out) ----------------
__global__ __launch_bounds__(192) void k_combine(
    const float* __restrict__ Op, const int* __restrict__ slot_of,
    const float* __restrict__ t2w, float* __restrict__ out) {
  int t = blockIdx.x;
  int d4 = threadIdx.x << 2;
  int s0 = slot_of[2 * t], s1 = slot_of[2 * t + 1];
  float w0 = t2w[2 * t], w1 = t2w[2 * t + 1];
  float4 a = *(const float4*)&Op[(size_t)s0 * DMODEL + d4];
  float4 b = *(const float4*)&Op[(size_t)s1 * DMODEL + d4];
  float4 r;
  r.x = w0 * a.x + w1 * b.x;
  r.y = w0 * a.y + w1 * b.y;
  r.z = w0 * a.z + w1 * b.z;
  r.w = w0 * a.w + w1 * b.w;
  *(float4*)&out[(size_t)t * DMODEL + d4] = r;
}

// ================= fallback (R2-proven, fp32 direct) =================
__device__ __forceinline__ void wpack(u32* lds, int k2, int n8, uint4 a, uint4 b) {
  int idx = n8 * WSTR + k2;
  lds[idx + 0 * WSTR] = (a.x & 0xffffu) | (b.x << 16);
  lds[idx + 1 * WSTR] = (a.x >> 16) | (b.x & 0xffff0000u);
  lds[idx + 2 * WSTR] = (a.y & 0xffffu) | (b.y << 16);
  lds[idx + 3 * WSTR] = (a.y >> 16) | (b.y & 0xffff0000u);
  lds[idx + 4 * WSTR] = (a.z & 0xffffu) | (b.z << 16);
  lds[idx + 5 * WSTR] = (a.z >> 16) | (b.z & 0xffff0000u);
  lds[idx + 6 * WSTR] = (a.w & 0xffffu) | (b.w << 16);
  lds[idx + 7 * WSTR] = (a.w >> 16) | (b.w & 0xffff0000u);
}

__global__ __launch_bounds__(256) void k_stage1f(
    const float* __restrict__ xv, const float* __restrict__ wgv, const float* __restrict__ wuv,
    const int* __restrict__ meta, const int* __restrict__ tok, u16* __restrict__ H) {
  __shared__ u16 Xs[64 * 32];
  __shared__ u16 Wgs[128 * BKP];
  __shared__ u16 Wus[128 * BKP];
  int e = blockIdx.z;
  int off_e = meta[M_OFF + e];
  int rows_e = meta[M_OFF + e + 1] - off_e;
  int r0 = blockIdx.y * 64;
  if (r0 >= rows_e) return;
  int rows_t = rows_e - r0; if (rows_t > 64) rows_t = 64;
  int f0 = blockIdx.x * 128;
  int tid = threadIdx.x, lane = tid & 63, w = tid >> 6;
  int wr = w >> 1, wc = w & 1;
  int srow = (w << 4) + (lane >> 2);
  int trow = (srow < rows_t) ? tok[off_e + r0 + srow] : tok[off_e];
  int xcol = (lane & 3) << 3;
  u16* xl = &Xs[srow * 32 + xcol];
  int k2 = tid >> 4, n8 = (tid & 15) << 3;
  size_t wbase = (size_t)e * (DMODEL * DFF) + (size_t)(k2 << 1) * DFF + f0 + n8;
  f32x4 accg[2][4], accu[2][4];
#pragma unroll
  for (int i = 0; i < 2; ++i)
#pragma unroll
    for (int j = 0; j < 4; ++j) {
      accg[i][j] = (f32x4){0.f, 0.f, 0.f, 0.f};
      accu[i][j] = (f32x4){0.f, 0.f, 0.f, 0.f};
    }
  for (int kk = 0; kk < DMODEL / 32; ++kk) {
    int k0 = kk << 5;
    const float* xg = xv + (size_t)trow * DMODEL + xcol;
    const float* wgp = wgv + wbase;
    const float* wup = wuv + wbase;
    uint4 xa = cvt8(*(const float4*)(xg + k0), *(const float4*)(xg + k0 + 4));
    uint4 ga = cvt8(*(const float4*)(wgp + (size_t)k0 * DFF), *(const float4*)(wgp + (size_t)k0 * DFF + 4));
    uint4 gb = cvt8(*(const float4*)(wgp + (size_t)k0 * DFF + DFF), *(const float4*)(wgp + (size_t)k0 * DFF + DFF + 4));
    uint4 ua = cvt8(*(const float4*)(wup + (size_t)k0 * DFF), *(const float4*)(wup + (size_t)k0 * DFF + 4));
    uint4 ub = cvt8(*(const float4*)(wup + (size_t)k0 * DFF + DFF), *(const float4*)(wup + (size_t)k0 * DFF + DFF + 4));
    __syncthreads();
    *(uint4*)xl = xa;
    wpack((u32*)Wgs, k2, n8, ga, gb);
    wpack((u32*)Wus, k2, n8, ua, ub);
    __syncthreads();
    short8 af[2];
#pragma unroll
    for (int mt = 0; mt < 2; ++mt)
      af[mt] = *(const short8*)&Xs[((wr << 5) + (mt << 4) + (lane & 15)) * 32 + ((lane >> 4) << 3)];
#pragma unroll
    for (int nt = 0; nt < 4; ++nt) {
      int col = (wc << 6) + (nt << 4) + (lane & 15);
      short8 bg = *(const short8*)&Wgs[col * BKP + ((lane >> 4) << 3)];
      short8 bu = *(const short8*)&Wus[col * BKP + ((lane >> 4) << 3)];
#pragma unroll
      for (int mt = 0; mt < 2; ++mt) {
        accg[mt][nt] = __builtin_amdgcn_mfma_f32_16x16x32_bf16(af[mt], bg, accg[mt][nt], 0, 0, 0);
        accu[mt][nt] = __builtin_amdgcn_mfma_f32_16x16x32_bf16(af[mt], bu, accu[mt][nt], 0, 0, 0);
      }
    }
  }
  int q = lane >> 4, c = lane & 15;
#pragma unroll
  for (int mt = 0; mt < 2; ++mt)
#pragma unroll
    for (int r = 0; r < 4; ++r) {
      int lrow = (wr << 5) + (mt << 4) + (q << 2) + r;
      if (lrow < rows_t) {
        size_t rowbase = (size_t)(off_e + r0 + lrow) * DFF + f0 + (wc << 6);
#pragma unroll
        for (int nt = 0; nt < 4; ++nt) {
          float g = accg[mt][nt][r], u = accu[mt][nt][r];
          float h = g / (1.f + __expf(-g)) * u;
          H[rowbase + (nt << 4) + c] = f2b(h);
        }
      }
    }
}

__global__ __launch_bounds__(256) void k_stage2f(
    const u16* __restrict__ H, const float* __restrict__ wdv,
    const int* __restrict__ meta, float* __restrict__ Op) {
  __shared__ u16 As[64 * 32];
  __shared__ u16 Ws[128 * BKP];
  int e = blockIdx.z;
  int off_e = meta[M_OFF + e];
  int rows_e = meta[M_OFF + e + 1] - off_e;
  int r0 = blockIdx.y * 64;
  if (r0 >= rows_e) return;
  int rows_t = rows_e - r0; if (rows_t > 64) rows_t = 64;
  int n0 = blockIdx.x * 128;
  int tid = threadIdx.x, lane = tid & 63, w = tid >> 6;
  int wr = w >> 1, wc = w & 1;
  int srow = (w << 4) + (lane >> 2);
  int hrow = off_e + r0 + ((srow < rows_t) ? srow : 0);
  const u16* ag = H + (size_t)hrow * DFF + ((lane & 3) << 3);
  u16* al = &As[srow * 32 + ((lane & 3) << 3)];
  int k2 = tid >> 4, n8 = (tid & 15) << 3;
  size_t wbase = (size_t)e * (DFF * DMODEL) + (size_t)(k2 << 1) * DMODEL + n0 + n8;
  f32x4 acc[2][4];
#pragma unroll
  for (int i = 0; i < 2; ++i)
#pragma unroll
    for (int j = 0; j < 4; ++j) acc[i][j] = (f32x4){0.f, 0.f, 0.f, 0.f};
  for (int kk = 0; kk < DFF / 32; ++kk) {
    int k0 = kk << 5;
    uint4 xa = *(const uint4*)(ag + k0);
    const float* wdp = wdv + wbase;
    uint4 ga = cvt8(*(const float4*)(wdp + (size_t)k0 * DMODEL), *(const float4*)(wdp + (size_t)k0 * DMODEL + 4));
    uint4 gb = cvt8(*(const float4*)(wdp + (size_t)k0 * DMODEL + DMODEL), *(const float4*)(wdp + (size_t)k0 * DMODEL + DMODEL + 4));
    __syncthreads();
    *(uint4*)al = xa;
    wpack((u32*)Ws, k2, n8, ga, gb);
    __syncthreads();
    short8 af[2];
#pragma unroll
    for (int mt = 0; mt < 2; ++mt)
      af[mt] = *(const short8*)&As[((wr << 5) + (mt << 4) + (lane & 15)) * 32 + ((lane >> 4) << 3)];
#pragma unroll
    for (int nt = 0; nt < 4; ++nt) {
      int col = (wc << 6) + (nt << 4) + (lane & 15);
      short8 b = *(const short8*)&Ws[col * BKP + ((lane >> 4) << 3)];
#pragma unroll
      for (int mt = 0; mt < 2; ++mt)
        acc[mt][nt] = __builtin_amdgcn_mfma_f32_16x16x32_bf16(af[mt], b, acc[mt][nt], 0, 0, 0);
    }
  }
  int q = lane >> 4, c = lane & 15;
#pragma unroll
  for (int mt = 0; mt < 2; ++mt)
#pragma unroll
    for (int r = 0; r < 4; ++r) {
      int lrow = (wr << 5) + (mt << 4) + (q << 2) + r;
      if (lrow < rows_t) {
        size_t rowbase = (size_t)(off_e + r0 + lrow) * DMODEL + n0 + (wc << 6);
#pragma unroll
        for (int nt = 0; nt < 4; ++nt)
          Op[rowbase + (nt << 4) + c] = acc[mt][nt][r];
      }
    }
}

extern "C" void kernel_launch(void* const* d_in, const int* in_sizes, int n_in,
                              void* d_out, int out_size, void* d_ws, size_t ws_size,
                              hipStream_t stream) {
  const float* x  = (const float*)d_in[0];
  const float* gw = (const float*)d_in[1];
  const float* wg = (const float*)d_in[2];
  const float* wu = (const float*)d_in[3];
  const float* wd = (const float*)d_in[4];
  float* out = (float*)d_out;

  char* ws = (char*)d_ws;
  int* meta = (int*)ws;
  int* t2e        = (int*)(ws + 256);
  int* slot_of    = (int*)(ws + 16640);
  int* tok_of_row = (int*)(ws + 33024);
  float* t2w      = (float*)(ws + 49408);

  k_init<<<1, 64, 0, stream>>>(meta);
  k_router<<<T_TOK / 4, 256, 0, stream>>>(x, gw, meta, t2e, t2w);
  k_scan<<<1, 64, 0, stream>>>(meta, out);
  k_scatter<<<T_TOK / 256, 256, 0, stream>>>(t2e, meta, tok_of_row, slot_of);

  const size_t NEED = 108069120;  // fast-path ws footprint
  if (ws_size >= NEED) {
    u16* Xb    = (u16*)(ws + 65792);                 // [2048*768] bf16
    u16* H     = (u16*)(ws + 3211520);               // [4096*2048] bf16
    float* Op  = (float*)(ws + 19988736);            // [4096*768] fp32
    u16* WgB   = (u16*)(ws + 32571648);              // blocked bf16
    u16* WuB   = (u16*)(ws + 57737472);
    u16* WdB   = (u16*)(ws + 82903296);

    k_xcvt<<<768, 256, 0, stream>>>(x, Xb);
    dim3 tg1(DFF / 128, DMODEL / 32, NEXP);   // (16,24,8)
    k_wtrans<<<tg1, 256, 0, stream>>>(wg, WgB, DMODEL, DFF);
    k_wtrans<<<tg1, 256, 0, stream>>>(wu, WuB, DMODEL, DFF);
    dim3 tg2(DMODEL / 128, DFF / 32, NEXP);   // (6,64,8)
    k_wtrans<<<tg2, 256, 0, stream>>>(wd, WdB, DFF, DMODEL);

    dim3 g1(16, 16, NEXP);  // 16 x-blocks: per-expert rows <= 2048
    k_stage1b<<<g1, 256, 0, stream>>>(Xb, WgB, WuB, meta, tok_of_row, H);
    dim3 g2(16, 6, NEXP);
    k_stage2b<<<g2, 256, 0, stream>>>(H, WdB, meta, Op);
    k_combine<<<T_TOK, 192, 0, stream>>>(Op, slot_of, t2w, out);
  } else {
    u16* H    = (u16*)(ws + 65792);
    float* Op = (float*)(ws + 65792 + 16777216);
    dim3 g1(DFF / 128, T_TOK / 64, NEXP);
    k_stage1f<<<g1, 256, 0, stream>>>(x, wg, wu, meta, tok_of_row, H);
    dim3 g2(DMODEL / 128, T_TOK / 64, NEXP);
    k_stage2f<<<g2, 256, 0, stream>>>(H, wd, meta, Op);
    k_combine<<<T_TOK, 192, 0, stream>>>(Op, slot_of, t2w, out);
  }
}

// Round 5
// 435.941 us; speedup vs baseline: 1.1218x; 1.0062x over previous
//
#include <hip/hip_runtime.h>
#include <stdint.h>

typedef __attribute__((ext_vector_type(8))) short short8;
typedef __attribute__((ext_vector_type(4))) float f32x4;
typedef unsigned int u32;
typedef unsigned short u16;

#define T_TOK 2048
#define DMODEL 768
#define DFF 2048
#define NEXP 8

#define BKP 40      // padded LDS row stride (elems): 20 u32 -> 2-way max bank alias (free)
#define WSTR 20     // (fallback wpack) uint stride per n-column

// meta ints: [0..7]=cnt [8..15]=cur [16..24]=off
#define M_CNT 0
#define M_CUR 8
#define M_OFF 16

__device__ __forceinline__ float b2f(u16 u) {
  union { u32 i; float f; } v; v.i = ((u32)u) << 16; return v.f;
}
__device__ __forceinline__ u16 f2b(float f) {
  union { float f; u32 i; } v; v.f = f;
  return (u16)((v.i + 0x7fffu + ((v.i >> 16) & 1u)) >> 16);
}
__device__ __forceinline__ u32 pack2(float lo, float hi) {
  return (u32)f2b(lo) | ((u32)f2b(hi) << 16);
}
__device__ __forceinline__ uint4 cvt8(float4 a, float4 b) {
  uint4 r; r.x = pack2(a.x, a.y); r.y = pack2(a.z, a.w);
  r.z = pack2(b.x, b.y); r.w = pack2(b.z, b.w); return r;
}

// ---------------- init ----------------
__global__ void k_init(int* __restrict__ meta) {
  if (threadIdx.x < NEXP) meta[M_CNT + threadIdx.x] = 0;
}

// ---------------- router: one wave per token (fp32 in) ----------------
__global__ __launch_bounds__(256) void k_router(
    const float* __restrict__ x, const float* __restrict__ gw,
    int* __restrict__ meta, int* __restrict__ t2e, float* __restrict__ t2w) {
  int lane = threadIdx.x & 63;
  int t = blockIdx.x * 4 + (threadIdx.x >> 6);
  const float* xr = x + (size_t)t * DMODEL;
  float acc[8];
#pragma unroll
  for (int e = 0; e < 8; ++e) acc[e] = 0.f;
#pragma unroll
  for (int i = 0; i < 12; ++i) {
    int d = lane + (i << 6);
    float xd = xr[d];
    float4 g0 = *(const float4*)(gw + d * 8);
    float4 g1 = *(const float4*)(gw + d * 8 + 4);
    acc[0] += xd * g0.x; acc[1] += xd * g0.y;
    acc[2] += xd * g0.z; acc[3] += xd * g0.w;
    acc[4] += xd * g1.x; acc[5] += xd * g1.y;
    acc[6] += xd * g1.z; acc[7] += xd * g1.w;
  }
#pragma unroll
  for (int s = 32; s >= 1; s >>= 1) {
#pragma unroll
    for (int e = 0; e < 8; ++e) acc[e] += __shfl_xor(acc[e], s);
  }
  if (lane == 0) {
    int i0 = 0;
#pragma unroll
    for (int e = 1; e < 8; ++e) if (acc[e] > acc[i0]) i0 = e;
    int i1 = (i0 == 0) ? 1 : 0;
#pragma unroll
    for (int e = 0; e < 8; ++e) if (e != i0 && acc[e] > acc[i1]) i1 = e;
    float w0 = 1.f / (1.f + __expf(acc[i1] - acc[i0]));
    t2e[2 * t] = i0; t2e[2 * t + 1] = i1;
    t2w[2 * t] = w0; t2w[2 * t + 1] = 1.f - w0;
    atomicAdd(&meta[M_CNT + i0], 1); atomicAdd(&meta[M_CNT + i1], 1);
  }
}

// ---------------- exclusive scan of 8 counts + loss=0 ----------------
__global__ void k_scan(int* __restrict__ meta, float* __restrict__ outp) {
  if (threadIdx.x == 0) {
    int r = 0;
    for (int e = 0; e < NEXP; ++e) {
      meta[M_OFF + e] = r; meta[M_CUR + e] = r; r += meta[M_CNT + e];
    }
    meta[M_OFF + NEXP] = r;
    outp[(size_t)T_TOK * DMODEL] = 0.f;  // load_balancing_loss
  }
}

// ---------------- scatter tokens into expert buckets ----------------
__global__ __launch_bounds__(256) void k_scatter(
    const int* __restrict__ t2e, int* __restrict__ meta,
    int* __restrict__ tok_of_row, int* __restrict__ slot_of) {
  int t = blockIdx.x * 256 + threadIdx.x;
#pragma unroll
  for (int k = 0; k < 2; ++k) {
    int e = t2e[2 * t + k];
    int r = atomicAdd(&meta[M_CUR + e], 1);
    tok_of_row[r] = t;
    slot_of[2 * t + k] = r;
  }
}

// ---------------- pre-pass: x fp32 -> bf16 ----------------
__global__ __launch_bounds__(256) void k_xcvt(const float* __restrict__ x, u16* __restrict__ xb) {
  size_t i = ((size_t)blockIdx.x * 256 + threadIdx.x) * 8;
  float4 a = *(const float4*)(x + i);
  float4 b = *(const float4*)(x + i + 4);
  *(uint4*)(xb + i) = cvt8(a, b);
}

// ---------------- pre-pass: W [e][K][N] fp32 -> blocked bf16 [e][N/128][K/32][128][32]
__global__ __launch_bounds__(256) void k_wtrans(
    const float* __restrict__ in, u16* __restrict__ out, int K, int N) {
  __shared__ float T[32][136];
  int e = blockIdx.z, nx = blockIdx.x, ky = blockIdx.y;
  int t = threadIdx.x;
  const float* ip = in + (size_t)e * K * N + (size_t)(ky * 32) * N + nx * 128;
  int kr = t >> 3, nc = (t & 7) * 16;
  const float* rp = ip + (size_t)kr * N + nc;
  float4 v0 = *(const float4*)(rp);
  float4 v1 = *(const float4*)(rp + 4);
  float4 v2 = *(const float4*)(rp + 8);
  float4 v3 = *(const float4*)(rp + 12);
  *(float4*)&T[kr][nc] = v0;
  *(float4*)&T[kr][nc + 4] = v1;
  *(float4*)&T[kr][nc + 8] = v2;
  *(float4*)&T[kr][nc + 12] = v3;
  __syncthreads();
  int nr = t >> 1, kh = (t & 1) * 16;
  float v[16];
#pragma unroll
  for (int j = 0; j < 16; ++j) v[j] = T[kh + j][nr];
  uint4 o0, o1;
  o0.x = pack2(v[0], v[1]);  o0.y = pack2(v[2], v[3]);
  o0.z = pack2(v[4], v[5]);  o0.w = pack2(v[6], v[7]);
  o1.x = pack2(v[8], v[9]);  o1.y = pack2(v[10], v[11]);
  o1.z = pack2(v[12], v[13]); o1.w = pack2(v[14], v[15]);
  int NB = N >> 7, KB = K >> 5;
  u16* op = out + ((size_t)(e * NB + nx) * KB + ky) * 4096 + nr * 32 + kh;
  *(uint4*)op = o0;
  *(uint4*)(op + 8) = o1;
}

// ---------------- stage 1 (fast): Xb @ [WgB|WuB] -> H = silu(g)*u ----------------
// tile 128 rows x 128 cols, BK=32, 4 waves 2x2, wave tile 64x64
// K-loop software-pipelined: iter k's MFMA overlaps iter k+1's global loads.
__global__ __launch_bounds__(256, 2) void k_stage1b(
    const u16* __restrict__ Xb, const u16* __restrict__ WgB, const u16* __restrict__ WuB,
    const int* __restrict__ meta, const int* __restrict__ tok, u16* __restrict__ H) {
  __shared__ u16 Xs[128 * BKP];
  __shared__ u16 Wgs[128 * BKP];
  __shared__ u16 Wus[128 * BKP];
  int e = blockIdx.z, fb = blockIdx.y;
  int off_e = meta[M_OFF + e];
  int rows_e = meta[M_OFF + e + 1] - off_e;
  int r0 = blockIdx.x * 128;
  if (r0 >= rows_e) return;
  int rows_t = rows_e - r0; if (rows_t > 128) rows_t = 128;
  int f0 = fb * 128;
  int tid = threadIdx.x, lane = tid & 63, w = tid >> 6;
  int wr = w >> 1, wc = w & 1, q = lane >> 4, lm = lane & 15;

  // A staging: 2 threads per row, 16 elems each
  int arow = tid >> 1, akh = (tid & 1) * 16;
  int trow = (arow < rows_t) ? tok[off_e + r0 + arow] : tok[off_e];
  const u16* xg = Xb + (size_t)trow * DMODEL + akh;
  u16* al = &Xs[arow * BKP + akh];
  // B staging: thread copies 16 contiguous elems of the 8KB chunk
  int bn = tid >> 1, bkh = (tid & 1) * 16;
  size_t chunk0 = (size_t)((e * 16 + fb) * 24) * 4096 + tid * 16;
  const u16* gsrc = WgB + chunk0;
  const u16* usrc = WuB + chunk0;
  u16* gl = &Wgs[bn * BKP + bkh];
  u16* ul = &Wus[bn * BKP + bkh];

  const u16* ap[4]; const u16* gp[4]; const u16* up[4];
#pragma unroll
  for (int mt = 0; mt < 4; ++mt) ap[mt] = &Xs[(wr * 64 + mt * 16 + lm) * BKP + q * 8];
#pragma unroll
  for (int nt = 0; nt < 4; ++nt) {
    gp[nt] = &Wgs[(wc * 64 + nt * 16 + lm) * BKP + q * 8];
    up[nt] = &Wus[(wc * 64 + nt * 16 + lm) * BKP + q * 8];
  }

  f32x4 accg[4][4], accu[4][4];
#pragma unroll
  for (int i = 0; i < 4; ++i)
#pragma unroll
    for (int j = 0; j < 4; ++j) {
      accg[i][j] = (f32x4){0.f, 0.f, 0.f, 0.f};
      accu[i][j] = (f32x4){0.f, 0.f, 0.f, 0.f};
    }

  const int NK = DMODEL / 32;
  // prologue: prefetch k=0
  uint4 pa0 = *(const uint4*)(xg);
  uint4 pa1 = *(const uint4*)(xg + 8);
  uint4 pg0 = *(const uint4*)(gsrc);
  uint4 pg1 = *(const uint4*)(gsrc + 8);
  uint4 pu0 = *(const uint4*)(usrc);
  uint4 pu1 = *(const uint4*)(usrc + 8);

  for (int kk = 0; kk < NK; ++kk) {
    __syncthreads();
    *(uint4*)al = pa0; *(uint4*)(al + 8) = pa1;
    *(uint4*)gl = pg0; *(uint4*)(gl + 8) = pg1;
    *(uint4*)ul = pu0; *(uint4*)(ul + 8) = pu1;
    __syncthreads();
    if (kk + 1 < NK) {   // issue next iter's loads; they land during MFMA below
      int k0 = (kk + 1) << 5;
      pa0 = *(const uint4*)(xg + k0);
      pa1 = *(const uint4*)(xg + k0 + 8);
      pg0 = *(const uint4*)(gsrc + (size_t)(kk + 1) * 4096);
      pg1 = *(const uint4*)(gsrc + (size_t)(kk + 1) * 4096 + 8);
      pu0 = *(const uint4*)(usrc + (size_t)(kk + 1) * 4096);
      pu1 = *(const uint4*)(usrc + (size_t)(kk + 1) * 4096 + 8);
    }
    short8 af[4];
#pragma unroll
    for (int mt = 0; mt < 4; ++mt) af[mt] = *(const short8*)ap[mt];
#pragma unroll
    for (int nt = 0; nt < 4; ++nt) {
      short8 bg = *(const short8*)gp[nt];
      short8 bu = *(const short8*)up[nt];
#pragma unroll
      for (int mt = 0; mt < 4; ++mt) {
        accg[mt][nt] = __builtin_amdgcn_mfma_f32_16x16x32_bf16(af[mt], bg, accg[mt][nt], 0, 0, 0);
        accu[mt][nt] = __builtin_amdgcn_mfma_f32_16x16x32_bf16(af[mt], bu, accu[mt][nt], 0, 0, 0);
      }
    }
  }
#pragma unroll
  for (int mt = 0; mt < 4; ++mt)
#pragma unroll
    for (int r = 0; r < 4; ++r) {
      int lrow = wr * 64 + mt * 16 + q * 4 + r;
      if (lrow < rows_t) {
        size_t rowbase = (size_t)(off_e + r0 + lrow) * DFF + f0 + wc * 64;
#pragma unroll
        for (int nt = 0; nt < 4; ++nt) {
          float g = accg[mt][nt][r], u = accu[mt][nt][r];
          float h = g / (1.f + __expf(-g)) * u;
          H[rowbase + nt * 16 + lm] = f2b(h);
        }
      }
    }
}

// ---------------- stage 2 (fast): H @ WdB -> Op fp32 (pipelined) ----------------
__global__ __launch_bounds__(256, 2) void k_stage2b(
    const u16* __restrict__ H, const u16* __restrict__ WdB,
    const int* __restrict__ meta, float* __restrict__ Op) {
  __shared__ u16 As[128 * BKP];
  __shared__ u16 Ws[128 * BKP];
  int e = blockIdx.z, nb = blockIdx.y;
  int off_e = meta[M_OFF + e];
  int rows_e = meta[M_OFF + e + 1] - off_e;
  int r0 = blockIdx.x * 128;
  if (r0 >= rows_e) return;
  int rows_t = rows_e - r0; if (rows_t > 128) rows_t = 128;
  int n0 = nb * 128;
  int tid = threadIdx.x, lane = tid & 63, w = tid >> 6;
  int wr = w >> 1, wc = w & 1, q = lane >> 4, lm = lane & 15;

  int arow = tid >> 1, akh = (tid & 1) * 16;
  int hrow = off_e + r0 + ((arow < rows_t) ? arow : 0);
  const u16* ag = H + (size_t)hrow * DFF + akh;
  u16* al = &As[arow * BKP + akh];
  size_t chunk0 = (size_t)((e * 6 + nb) * 64) * 4096 + tid * 16;
  const u16* wsrc = WdB + chunk0;
  int bn = tid >> 1, bkh = (tid & 1) * 16;
  u16* wl = &Ws[bn * BKP + bkh];

  const u16* ap[4]; const u16* bp[4];
#pragma unroll
  for (int mt = 0; mt < 4; ++mt) ap[mt] = &As[(wr * 64 + mt * 16 + lm) * BKP + q * 8];
#pragma unroll
  for (int nt = 0; nt < 4; ++nt) bp[nt] = &Ws[(wc * 64 + nt * 16 + lm) * BKP + q * 8];

  f32x4 acc[4][4];
#pragma unroll
  for (int i = 0; i < 4; ++i)
#pragma unroll
    for (int j = 0; j < 4; ++j) acc[i][j] = (f32x4){0.f, 0.f, 0.f, 0.f};

  const int NK = DFF / 32;
  uint4 pa0 = *(const uint4*)(ag);
  uint4 pa1 = *(const uint4*)(ag + 8);
  uint4 pb0 = *(const uint4*)(wsrc);
  uint4 pb1 = *(const uint4*)(wsrc + 8);

  for (int kk = 0; kk < NK; ++kk) {
    __syncthreads();
    *(uint4*)al = pa0; *(uint4*)(al + 8) = pa1;
    *(uint4*)wl = pb0; *(uint4*)(wl + 8) = pb1;
    __syncthreads();
    if (kk + 1 < NK) {
      int k0 = (kk + 1) << 5;
      pa0 = *(const uint4*)(ag + k0);
      pa1 = *(const uint4*)(ag + k0 + 8);
      pb0 = *(const uint4*)(wsrc + (size_t)(kk + 1) * 4096);
      pb1 = *(const uint4*)(wsrc + (size_t)(kk + 1) * 4096 + 8);
    }
    short8 af[4];
#pragma unroll
    for (int mt = 0; mt < 4; ++mt) af[mt] = *(const short8*)ap[mt];
#pragma unroll
    for (int nt = 0; nt < 4; ++nt) {
      short8 b = *(const short8*)bp[nt];
#pragma unroll
      for (int mt = 0; mt < 4; ++mt)
        acc[mt][nt] = __builtin_amdgcn_mfma_f32_16x16x32_bf16(af[mt], b, acc[mt][nt], 0, 0, 0);
    }
  }
#pragma unroll
  for (int mt = 0; mt < 4; ++mt)
#pragma unroll
    for (int r = 0; r < 4; ++r) {
      int lrow = wr * 64 + mt * 16 + q * 4 + r;
      if (lrow < rows_t) {
        size_t rowbase = (size_t)(off_e + r0 + lrow) * DMODEL + n0 + wc * 64;
#pragma unroll
        for (int nt = 0; nt < 4; ++nt)
          Op[rowbase + nt * 16 + lm] = acc[mt][nt][r];
      }
    }
}

// ---------------- combine: out[t] = w0*Op[slot0] + w1*Op[slot1] (fp32 out) ----------------
__global__ __launch_bounds__(192) void k_combine(
    const float* __restrict__ Op, const int* __restrict__ slot_of,
    const float* __restrict__ t2w, float* __restrict__ out) {
  int t = blockIdx.x;
  int d4 = threadIdx.x << 2;
  int s0 = slot_of[2 * t], s1 = slot_of[2 * t + 1];
  float w0 = t2w[2 * t], w1 = t2w[2 * t + 1];
  float4 a = *(const float4*)&Op[(size_t)s0 * DMODEL + d4];
  float4 b = *(const float4*)&Op[(size_t)s1 * DMODEL + d4];
  float4 r;
  r.x = w0 * a.x + w1 * b.x;
  r.y = w0 * a.y + w1 * b.y;
  r.z = w0 * a.z + w1 * b.z;
  r.w = w0 * a.w + w1 * b.w;
  *(float4*)&out[(size_t)t * DMODEL + d4] = r;
}

// ================= fallback (R2-proven, fp32 direct) =================
__device__ __forceinline__ void wpack(u32* lds, int k2, int n8, uint4 a, uint4 b) {
  int idx = n8 * WSTR + k2;
  lds[idx + 0 * WSTR] = (a.x & 0xffffu) | (b.x << 16);
  lds[idx + 1 * WSTR] = (a.x >> 16) | (b.x & 0xffff0000u);
  lds[idx + 2 * WSTR] = (a.y & 0xffffu) | (b.y << 16);
  lds[idx + 3 * WSTR] = (a.y >> 16) | (b.y & 0xffff0000u);
  lds[idx + 4 * WSTR] = (a.z & 0xffffu) | (b.z << 16);
  lds[idx + 5 * WSTR] = (a.z >> 16) | (b.z & 0xffff0000u);
  lds[idx + 6 * WSTR] = (a.w & 0xffffu) | (b.w << 16);
  lds[idx + 7 * WSTR] = (a.w >> 16) | (b.w & 0xffff0000u);
}

__global__ __launch_bounds__(256) void k_stage1f(
    const float* __restrict__ xv, const float* __restrict__ wgv, const float* __restrict__ wuv,
    const int* __restrict__ meta, const int* __restrict__ tok, u16* __restrict__ H) {
  __shared__ u16 Xs[64 * 32];
  __shared__ u16 Wgs[128 * BKP];
  __shared__ u16 Wus[128 * BKP];
  int e = blockIdx.z;
  int off_e = meta[M_OFF + e];
  int rows_e = meta[M_OFF + e + 1] - off_e;
  int r0 = blockIdx.y * 64;
  if (r0 >= rows_e) return;
  int rows_t = rows_e - r0; if (rows_t > 64) rows_t = 64;
  int f0 = blockIdx.x * 128;
  int tid = threadIdx.x, lane = tid & 63, w = tid >> 6;
  int wr = w >> 1, wc = w & 1;
  int srow = (w << 4) + (lane >> 2);
  int trow = (srow < rows_t) ? tok[off_e + r0 + srow] : tok[off_e];
  int xcol = (lane & 3) << 3;
  u16* xl = &Xs[srow * 32 + xcol];
  int k2 = tid >> 4, n8 = (tid & 15) << 3;
  size_t wbase = (size_t)e * (DMODEL * DFF) + (size_t)(k2 << 1) * DFF + f0 + n8;
  f32x4 accg[2][4], accu[2][4];
#pragma unroll
  for (int i = 0; i < 2; ++i)
#pragma unroll
    for (int j = 0; j < 4; ++j) {
      accg[i][j] = (f32x4){0.f, 0.f, 0.f, 0.f};
      accu[i][j] = (f32x4){0.f, 0.f, 0.f, 0.f};
    }
  for (int kk = 0; kk < DMODEL / 32; ++kk) {
    int k0 = kk << 5;
    const float* xg = xv + (size_t)trow * DMODEL + xcol;
    const float* wgp = wgv + wbase;
    const float* wup = wuv + wbase;
    uint4 xa = cvt8(*(const float4*)(xg + k0), *(const float4*)(xg + k0 + 4));
    uint4 ga = cvt8(*(const float4*)(wgp + (size_t)k0 * DFF), *(const float4*)(wgp + (size_t)k0 * DFF + 4));
    uint4 gb = cvt8(*(const float4*)(wgp + (size_t)k0 * DFF + DFF), *(const float4*)(wgp + (size_t)k0 * DFF + DFF + 4));
    uint4 ua = cvt8(*(const float4*)(wup + (size_t)k0 * DFF), *(const float4*)(wup + (size_t)k0 * DFF + 4));
    uint4 ub = cvt8(*(const float4*)(wup + (size_t)k0 * DFF + DFF), *(const float4*)(wup + (size_t)k0 * DFF + DFF + 4));
    __syncthreads();
    *(uint4*)xl = xa;
    wpack((u32*)Wgs, k2, n8, ga, gb);
    wpack((u32*)Wus, k2, n8, ua, ub);
    __syncthreads();
    short8 af[2];
#pragma unroll
    for (int mt = 0; mt < 2; ++mt)
      af[mt] = *(const short8*)&Xs[((wr << 5) + (mt << 4) + (lane & 15)) * 32 + ((lane >> 4) << 3)];
#pragma unroll
    for (int nt = 0; nt < 4; ++nt) {
      int col = (wc << 6) + (nt << 4) + (lane & 15);
      short8 bg = *(const short8*)&Wgs[col * BKP + ((lane >> 4) << 3)];
      short8 bu = *(const short8*)&Wus[col * BKP + ((lane >> 4) << 3)];
#pragma unroll
      for (int mt = 0; mt < 2; ++mt) {
        accg[mt][nt] = __builtin_amdgcn_mfma_f32_16x16x32_bf16(af[mt], bg, accg[mt][nt], 0, 0, 0);
        accu[mt][nt] = __builtin_amdgcn_mfma_f32_16x16x32_bf16(af[mt], bu, accu[mt][nt], 0, 0, 0);
      }
    }
  }
  int q = lane >> 4, c = lane & 15;
#pragma unroll
  for (int mt = 0; mt < 2; ++mt)
#pragma unroll
    for (int r = 0; r < 4; ++r) {
      int lrow = (wr << 5) + (mt << 4) + (q << 2) + r;
      if (lrow < rows_t) {
        size_t rowbase = (size_t)(off_e + r0 + lrow) * DFF + f0 + (wc << 6);
#pragma unroll
        for (int nt = 0; nt < 4; ++nt) {
          float g = accg[mt][nt][r], u = accu[mt][nt][r];
          float h = g / (1.f + __expf(-g)) * u;
          H[rowbase + (nt << 4) + c] = f2b(h);
        }
      }
    }
}

__global__ __launch_bounds__(256) void k_stage2f(
    const u16* __restrict__ H, const float* __restrict__ wdv,
    const int* __restrict__ meta, float* __restrict__ Op) {
  __shared__ u16 As[64 * 32];
  __shared__ u16 Ws[128 * BKP];
  int e = blockIdx.z;
  int off_e = meta[M_OFF + e];
  int rows_e = meta[M_OFF + e + 1] - off_e;
  int r0 = blockIdx.y * 64;
  if (r0 >= rows_e) return;
  int rows_t = rows_e - r0; if (rows_t > 64) rows_t = 64;
  int n0 = blockIdx.x * 128;
  int tid = threadIdx.x, lane = tid & 63, w = tid >> 6;
  int wr = w >> 1, wc = w & 1;
  int srow = (w << 4) + (lane >> 2);
  int hrow = off_e + r0 + ((srow < rows_t) ? srow : 0);
  const u16* ag = H + (size_t)hrow * DFF + ((lane & 3) << 3);
  u16* al = &As[srow * 32 + ((lane & 3) << 3)];
  int k2 = tid >> 4, n8 = (tid & 15) << 3;
  size_t wbase = (size_t)e * (DFF * DMODEL) + (size_t)(k2 << 1) * DMODEL + n0 + n8;
  f32x4 acc[2][4];
#pragma unroll
  for (int i = 0; i < 2; ++i)
#pragma unroll
    for (int j = 0; j < 4; ++j) acc[i][j] = (f32x4){0.f, 0.f, 0.f, 0.f};
  for (int kk = 0; kk < DFF / 32; ++kk) {
    int k0 = kk << 5;
    uint4 xa = *(const uint4*)(ag + k0);
    const float* wdp = wdv + wbase;
    uint4 ga = cvt8(*(const float4*)(wdp + (size_t)k0 * DMODEL), *(const float4*)(wdp + (size_t)k0 * DMODEL + 4));
    uint4 gb = cvt8(*(const float4*)(wdp + (size_t)k0 * DMODEL + DMODEL), *(const float4*)(wdp + (size_t)k0 * DMODEL + DMODEL + 4));
    __syncthreads();
    *(uint4*)al = xa;
    wpack((u32*)Ws, k2, n8, ga, gb);
    __syncthreads();
    short8 af[2];
#pragma unroll
    for (int mt = 0; mt < 2; ++mt)
      af[mt] = *(const short8*)&As[((wr << 5) + (mt << 4) + (lane & 15)) * 32 + ((lane >> 4) << 3)];
#pragma unroll
    for (int nt = 0; nt < 4; ++nt) {
      int col = (wc << 6) + (nt << 4) + (lane & 15);
      short8 b = *(const short8*)&Ws[col * BKP + ((lane >> 4) << 3)];
#pragma unroll
      for (int mt = 0; mt < 2; ++mt)
        acc[mt][nt] = __builtin_amdgcn_mfma_f32_16x16x32_bf16(af[mt], b, acc[mt][nt], 0, 0, 0);
    }
  }
  int q = lane >> 4, c = lane & 15;
#pragma unroll
  for (int mt = 0; mt < 2; ++mt)
#pragma unroll
    for (int r = 0; r < 4; ++r) {
      int lrow = (wr << 5) + (mt << 4) + (q << 2) + r;
      if (lrow < rows_t) {
        size_t rowbase = (size_t)(off_e + r0 + lrow) * DMODEL + n0 + (wc << 6);
#pragma unroll
        for (int nt = 0; nt < 4; ++nt)
          Op[rowbase + (nt << 4) + c] = acc[mt][nt][r];
      }
    }
}

extern "C" void kernel_launch(void* const* d_in, const int* in_sizes, int n_in,
                              void* d_out, int out_size, void* d_ws, size_t ws_size,
                              hipStream_t stream) {
  const float* x  = (const float*)d_in[0];
  const float* gw = (const float*)d_in[1];
  const float* wg = (const float*)d_in[2];
  const float* wu = (const float*)d_in[3];
  const float* wd = (const float*)d_in[4];
  float* out = (float*)d_out;

  char* ws = (char*)d_ws;
  int* meta = (int*)ws;
  int* t2e        = (int*)(ws + 256);
  int* slot_of    = (int*)(ws + 16640);
  int* tok_of_row = (int*)(ws + 33024);
  float* t2w      = (float*)(ws + 49408);

  k_init<<<1, 64, 0, stream>>>(meta);
  k_router<<<T_TOK / 4, 256, 0, stream>>>(x, gw, meta, t2e, t2w);
  k_scan<<<1, 64, 0, stream>>>(meta, out);
  k_scatter<<<T_TOK / 256, 256, 0, stream>>>(t2e, meta, tok_of_row, slot_of);

  const size_t NEED = 108069120;  // fast-path ws footprint
  if (ws_size >= NEED) {
    u16* Xb    = (u16*)(ws + 65792);                 // [2048*768] bf16
    u16* H     = (u16*)(ws + 3211520);               // [4096*2048] bf16
    float* Op  = (float*)(ws + 19988736);            // [4096*768] fp32
    u16* WgB   = (u16*)(ws + 32571648);              // blocked bf16
    u16* WuB   = (u16*)(ws + 57737472);
    u16* WdB   = (u16*)(ws + 82903296);

    k_xcvt<<<768, 256, 0, stream>>>(x, Xb);
    dim3 tg1(DFF / 128, DMODEL / 32, NEXP);   // (16,24,8)
    k_wtrans<<<tg1, 256, 0, stream>>>(wg, WgB, DMODEL, DFF);
    k_wtrans<<<tg1, 256, 0, stream>>>(wu, WuB, DMODEL, DFF);
    dim3 tg2(DMODEL / 128, DFF / 32, NEXP);   // (6,64,8)
    k_wtrans<<<tg2, 256, 0, stream>>>(wd, WdB, DFF, DMODEL);

    dim3 g1(16, 16, NEXP);  // 16 x-blocks: per-expert rows <= 2048
    k_stage1b<<<g1, 256, 0, stream>>>(Xb, WgB, WuB, meta, tok_of_row, H);
    dim3 g2(16, 6, NEXP);
    k_stage2b<<<g2, 256, 0, stream>>>(H, WdB, meta, Op);
    k_combine<<<T_TOK, 192, 0, stream>>>(Op, slot_of, t2w, out);
  } else {
    u16* H    = (u16*)(ws + 65792);
    float* Op = (float*)(ws + 65792 + 16777216);
    dim3 g1(DFF / 128, T_TOK / 64, NEXP);
    k_stage1f<<<g1, 256, 0, stream>>>(x, wg, wu, meta, tok_of_row, H);
    dim3 g2(DMODEL / 128, T_TOK / 64, NEXP);
    k_stage2f<<<g2, 256, 0, stream>>>(H, wd, meta, Op);
    k_combine<<<T_TOK, 192, 0, stream>>>(Op, slot_of, t2w, out);
  }
}

// Round 6
// 402.516 us; speedup vs baseline: 1.2150x; 1.0830x over previous
//
#include <hip/hip_runtime.h>
#include <stdint.h>

typedef __attribute__((ext_vector_type(8))) short short8;
typedef __attribute__((ext_vector_type(4))) float f32x4;
typedef unsigned int u32;
typedef unsigned short u16;

#define T_TOK 2048
#define DMODEL 768
#define DFF 2048
#define NEXP 8

#define BKP 40      // (fallback path) padded LDS row stride
#define WSTR 20     // (fallback wpack) uint stride per n-column

// meta ints: [0..7]=cnt [8..15]=cur [16..24]=off
#define M_CNT 0
#define M_CUR 8
#define M_OFF 16

__device__ __forceinline__ float b2f(u16 u) {
  union { u32 i; float f; } v; v.i = ((u32)u) << 16; return v.f;
}
__device__ __forceinline__ u16 f2b(float f) {
  union { float f; u32 i; } v; v.f = f;
  return (u16)((v.i + 0x7fffu + ((v.i >> 16) & 1u)) >> 16);
}
__device__ __forceinline__ u32 pack2(float lo, float hi) {
  return (u32)f2b(lo) | ((u32)f2b(hi) << 16);
}
__device__ __forceinline__ uint4 cvt8(float4 a, float4 b) {
  uint4 r; r.x = pack2(a.x, a.y); r.y = pack2(a.z, a.w);
  r.z = pack2(b.x, b.y); r.w = pack2(b.z, b.w); return r;
}
// async global->LDS, 16B per lane; LDS dst = wave-uniform base + lane*16
__device__ __forceinline__ void gl16(const u16* g, u16* l) {
  __builtin_amdgcn_global_load_lds((const __attribute__((address_space(1))) void*)g,
                                   (__attribute__((address_space(3))) void*)l, 16, 0, 0);
}

// ---------------- init ----------------
__global__ void k_init(int* __restrict__ meta) {
  if (threadIdx.x < NEXP) meta[M_CNT + threadIdx.x] = 0;
}

// ---------------- router: one wave per token (fp32 in); also emits Xb bf16 ----------------
__global__ __launch_bounds__(256) void k_router(
    const float* __restrict__ x, const float* __restrict__ gw,
    int* __restrict__ meta, int* __restrict__ t2e, float* __restrict__ t2w,
    u16* __restrict__ xb) {
  int lane = threadIdx.x & 63;
  int t = blockIdx.x * 4 + (threadIdx.x >> 6);
  const float* xr = x + (size_t)t * DMODEL;
  u16* xbr = xb + (size_t)t * DMODEL;
  float acc[8];
#pragma unroll
  for (int e = 0; e < 8; ++e) acc[e] = 0.f;
#pragma unroll
  for (int i = 0; i < 12; ++i) {
    int d = lane + (i << 6);
    float xd = xr[d];
    xbr[d] = f2b(xd);
    float4 g0 = *(const float4*)(gw + d * 8);
    float4 g1 = *(const float4*)(gw + d * 8 + 4);
    acc[0] += xd * g0.x; acc[1] += xd * g0.y;
    acc[2] += xd * g0.z; acc[3] += xd * g0.w;
    acc[4] += xd * g1.x; acc[5] += xd * g1.y;
    acc[6] += xd * g1.z; acc[7] += xd * g1.w;
  }
#pragma unroll
  for (int s = 32; s >= 1; s >>= 1) {
#pragma unroll
    for (int e = 0; e < 8; ++e) acc[e] += __shfl_xor(acc[e], s);
  }
  if (lane == 0) {
    int i0 = 0;
#pragma unroll
    for (int e = 1; e < 8; ++e) if (acc[e] > acc[i0]) i0 = e;
    int i1 = (i0 == 0) ? 1 : 0;
#pragma unroll
    for (int e = 0; e < 8; ++e) if (e != i0 && acc[e] > acc[i1]) i1 = e;
    float w0 = 1.f / (1.f + __expf(acc[i1] - acc[i0]));
    t2e[2 * t] = i0; t2e[2 * t + 1] = i1;
    t2w[2 * t] = w0; t2w[2 * t + 1] = 1.f - w0;
    atomicAdd(&meta[M_CNT + i0], 1); atomicAdd(&meta[M_CNT + i1], 1);
  }
}

// ---------------- exclusive scan of 8 counts + loss=0 ----------------
__global__ void k_scan(int* __restrict__ meta, float* __restrict__ outp) {
  if (threadIdx.x == 0) {
    int r = 0;
    for (int e = 0; e < NEXP; ++e) {
      meta[M_OFF + e] = r; meta[M_CUR + e] = r; r += meta[M_CNT + e];
    }
    meta[M_OFF + NEXP] = r;
    outp[(size_t)T_TOK * DMODEL] = 0.f;  // load_balancing_loss
  }
}

// ---------------- scatter tokens into expert buckets ----------------
__global__ __launch_bounds__(256) void k_scatter(
    const int* __restrict__ t2e, int* __restrict__ meta,
    int* __restrict__ tok_of_row, int* __restrict__ slot_of) {
  int t = blockIdx.x * 256 + threadIdx.x;
#pragma unroll
  for (int k = 0; k < 2; ++k) {
    int e = t2e[2 * t + k];
    int r = atomicAdd(&meta[M_CUR + e], 1);
    tok_of_row[r] = t;
    slot_of[2 * t + k] = r;
  }
}

// ---------------- pre-pass: W [e][K][N] fp32 -> blocked bf16 [e][N/128][K/32][128][32]
__global__ __launch_bounds__(256) void k_wtrans(
    const float* __restrict__ in, u16* __restrict__ out, int K, int N) {
  __shared__ float T[32][136];
  int e = blockIdx.z, nx = blockIdx.x, ky = blockIdx.y;
  int t = threadIdx.x;
  const float* ip = in + (size_t)e * K * N + (size_t)(ky * 32) * N + nx * 128;
  int kr = t >> 3, nc = (t & 7) * 16;
  const float* rp = ip + (size_t)kr * N + nc;
  float4 v0 = *(const float4*)(rp);
  float4 v1 = *(const float4*)(rp + 4);
  float4 v2 = *(const float4*)(rp + 8);
  float4 v3 = *(const float4*)(rp + 12);
  *(float4*)&T[kr][nc] = v0;
  *(float4*)&T[kr][nc + 4] = v1;
  *(float4*)&T[kr][nc + 8] = v2;
  *(float4*)&T[kr][nc + 12] = v3;
  __syncthreads();
  int nr = t >> 1, kh = (t & 1) * 16;
  float v[16];
#pragma unroll
  for (int j = 0; j < 16; ++j) v[j] = T[kh + j][nr];
  uint4 o0, o1;
  o0.x = pack2(v[0], v[1]);  o0.y = pack2(v[2], v[3]);
  o0.z = pack2(v[4], v[5]);  o0.w = pack2(v[6], v[7]);
  o1.x = pack2(v[8], v[9]);  o1.y = pack2(v[10], v[11]);
  o1.z = pack2(v[12], v[13]); o1.w = pack2(v[14], v[15]);
  int NB = N >> 7, KB = K >> 5;
  u16* op = out + ((size_t)(e * NB + nx) * KB + ky) * 4096 + nr * 32 + kh;
  *(uint4*)op = o0;
  *(uint4*)(op + 8) = o1;
}

// ---------------- stage 1 (fast): Xb @ [WgB|WuB] -> H = silu(g)*u ----------------
// tile 128x128, BK=64 (2x 32-chunks), DMA staging via global_load_lds, no ds_writes.
__global__ __launch_bounds__(256, 2) void k_stage1b(
    const u16* __restrict__ Xb, const u16* __restrict__ WgB, const u16* __restrict__ WuB,
    const int* __restrict__ meta, const int* __restrict__ tok, u16* __restrict__ H) {
  __shared__ u16 Xs[8192];   // [2 sub][128 rows][32 k]
  __shared__ u16 Wgs[8192];
  __shared__ u16 Wus[8192];
  int e = blockIdx.z, fb = blockIdx.y;
  int off_e = meta[M_OFF + e];
  int rows_e = meta[M_OFF + e + 1] - off_e;
  int r0 = blockIdx.x * 128;
  if (r0 >= rows_e) return;
  int rows_t = rows_e - r0; if (rows_t > 128) rows_t = 128;
  int f0 = fb * 128;
  int tid = threadIdx.x, lane = tid & 63, w = tid >> 6;
  int wr = w >> 1, wc = w & 1, q = lane >> 4, lm = lane & 15;

  // DMA lane mapping: instr j covers rows (w*2+j)*16 + lane/4, granule lane&3
  int g4 = lane & 3, rsub = lane >> 2;
  int row0 = (w * 2) * 16 + rsub, row1 = row0 + 16;
  int cr0 = (row0 < rows_t) ? row0 : (rows_t - 1);
  int cr1 = (row1 < rows_t) ? row1 : (rows_t - 1);
  const u16* aG0 = Xb + (size_t)tok[off_e + r0 + cr0] * DMODEL + g4 * 8;
  const u16* aG1 = Xb + (size_t)tok[off_e + r0 + cr1] * DMODEL + g4 * 8;
  size_t cb = (size_t)((e * 16 + fb) * 24) * 4096 + (w * 2) * 512 + lane * 8;
  const u16* gG = WgB + cb;
  const u16* uG = WuB + cb;
  u16* aL0 = &Xs[(w * 2) * 512];
  u16* aL1 = aL0 + 512;
  u16* gL0 = &Wgs[(w * 2) * 512];
  u16* uL0 = &Wus[(w * 2) * 512];

  const u16* apb = &Xs[(wr * 64 + lm) * 32 + q * 8];
  const u16* gpb = &Wgs[(wc * 64 + lm) * 32 + q * 8];
  const u16* upb = &Wus[(wc * 64 + lm) * 32 + q * 8];

  f32x4 accg[4][4], accu[4][4];
#pragma unroll
  for (int i = 0; i < 4; ++i)
#pragma unroll
    for (int j = 0; j < 4; ++j) {
      accg[i][j] = (f32x4){0.f, 0.f, 0.f, 0.f};
      accu[i][j] = (f32x4){0.f, 0.f, 0.f, 0.f};
    }

  for (int kko = 0; kko < DMODEL / 64; ++kko) {
    int ka = kko * 64;
    size_t kb = (size_t)kko * 8192;
    gl16(aG0 + ka, aL0);            gl16(aG1 + ka, aL1);
    gl16(aG0 + ka + 32, aL0 + 4096); gl16(aG1 + ka + 32, aL1 + 4096);
    gl16(gG + kb, gL0);              gl16(gG + kb + 512, gL0 + 512);
    gl16(gG + kb + 4096, gL0 + 4096); gl16(gG + kb + 4608, gL0 + 4608);
    gl16(uG + kb, uL0);              gl16(uG + kb + 512, uL0 + 512);
    gl16(uG + kb + 4096, uL0 + 4096); gl16(uG + kb + 4608, uL0 + 4608);
    __syncthreads();   // drains vmcnt -> all DMA landed
#pragma unroll
    for (int s = 0; s < 2; ++s) {
      short8 af[4];
#pragma unroll
      for (int mt = 0; mt < 4; ++mt) af[mt] = *(const short8*)(apb + s * 4096 + mt * 512);
#pragma unroll
      for (int nt = 0; nt < 4; ++nt) {
        short8 bg = *(const short8*)(gpb + s * 4096 + nt * 512);
        short8 bu = *(const short8*)(upb + s * 4096 + nt * 512);
#pragma unroll
        for (int mt = 0; mt < 4; ++mt) {
          accg[mt][nt] = __builtin_amdgcn_mfma_f32_16x16x32_bf16(af[mt], bg, accg[mt][nt], 0, 0, 0);
          accu[mt][nt] = __builtin_amdgcn_mfma_f32_16x16x32_bf16(af[mt], bu, accu[mt][nt], 0, 0, 0);
        }
      }
    }
    __syncthreads();   // LDS consumed, safe to overwrite next iter
  }
#pragma unroll
  for (int mt = 0; mt < 4; ++mt)
#pragma unroll
    for (int r = 0; r < 4; ++r) {
      int lrow = wr * 64 + mt * 16 + q * 4 + r;
      if (lrow < rows_t) {
        size_t rowbase = (size_t)(off_e + r0 + lrow) * DFF + f0 + wc * 64;
#pragma unroll
        for (int nt = 0; nt < 4; ++nt) {
          float g = accg[mt][nt][r], u = accu[mt][nt][r];
          float h = g / (1.f + __expf(-g)) * u;
          H[rowbase + nt * 16 + lm] = f2b(h);
        }
      }
    }
}

// ---------------- stage 2 (fast): H @ WdB -> Op fp32 (DMA staging, BK=64) ----------------
__global__ __launch_bounds__(256, 2) void k_stage2b(
    const u16* __restrict__ H, const u16* __restrict__ WdB,
    const int* __restrict__ meta, float* __restrict__ Op) {
  __shared__ u16 As[8192];
  __shared__ u16 Ws[8192];
  int e = blockIdx.z, nb = blockIdx.y;
  int off_e = meta[M_OFF + e];
  int rows_e = meta[M_OFF + e + 1] - off_e;
  int r0 = blockIdx.x * 128;
  if (r0 >= rows_e) return;
  int rows_t = rows_e - r0; if (rows_t > 128) rows_t = 128;
  int n0 = nb * 128;
  int tid = threadIdx.x, lane = tid & 63, w = tid >> 6;
  int wr = w >> 1, wc = w & 1, q = lane >> 4, lm = lane & 15;

  int g4 = lane & 3, rsub = lane >> 2;
  int row0 = (w * 2) * 16 + rsub, row1 = row0 + 16;
  int cr0 = (row0 < rows_t) ? row0 : (rows_t - 1);
  int cr1 = (row1 < rows_t) ? row1 : (rows_t - 1);
  const u16* aG0 = H + (size_t)(off_e + r0 + cr0) * DFF + g4 * 8;
  const u16* aG1 = H + (size_t)(off_e + r0 + cr1) * DFF + g4 * 8;
  size_t cb = (size_t)((e * 6 + nb) * 64) * 4096 + (w * 2) * 512 + lane * 8;
  const u16* wG = WdB + cb;
  u16* aL0 = &As[(w * 2) * 512];
  u16* aL1 = aL0 + 512;
  u16* wL0 = &Ws[(w * 2) * 512];

  const u16* apb = &As[(wr * 64 + lm) * 32 + q * 8];
  const u16* bpb = &Ws[(wc * 64 + lm) * 32 + q * 8];

  f32x4 acc[4][4];
#pragma unroll
  for (int i = 0; i < 4; ++i)
#pragma unroll
    for (int j = 0; j < 4; ++j) acc[i][j] = (f32x4){0.f, 0.f, 0.f, 0.f};

  for (int kko = 0; kko < DFF / 64; ++kko) {
    int ka = kko * 64;
    size_t kb = (size_t)kko * 8192;
    gl16(aG0 + ka, aL0);             gl16(aG1 + ka, aL1);
    gl16(aG0 + ka + 32, aL0 + 4096); gl16(aG1 + ka + 32, aL1 + 4096);
    gl16(wG + kb, wL0);              gl16(wG + kb + 512, wL0 + 512);
    gl16(wG + kb + 4096, wL0 + 4096); gl16(wG + kb + 4608, wL0 + 4608);
    __syncthreads();
#pragma unroll
    for (int s = 0; s < 2; ++s) {
      short8 af[4];
#pragma unroll
      for (int mt = 0; mt < 4; ++mt) af[mt] = *(const short8*)(apb + s * 4096 + mt * 512);
#pragma unroll
      for (int nt = 0; nt < 4; ++nt) {
        short8 b = *(const short8*)(bpb + s * 4096 + nt * 512);
#pragma unroll
        for (int mt = 0; mt < 4; ++mt)
          acc[mt][nt] = __builtin_amdgcn_mfma_f32_16x16x32_bf16(af[mt], b, acc[mt][nt], 0, 0, 0);
      }
    }
    __syncthreads();
  }
#pragma unroll
  for (int mt = 0; mt < 4; ++mt)
#pragma unroll
    for (int r = 0; r < 4; ++r) {
      int lrow = wr * 64 + mt * 16 + q * 4 + r;
      if (lrow < rows_t) {
        size_t rowbase = (size_t)(off_e + r0 + lrow) * DMODEL + n0 + wc * 64;
#pragma unroll
        for (int nt = 0; nt < 4; ++nt)
          Op[rowbase + nt * 16 + lm] = acc[mt][nt][r];
      }
    }
}

// ---------------- combine: out[t] = w0*Op[slot0] + w1*Op[slot1] (fp32 out) ----------------
__global__ __launch_bounds__(192) void k_combine(
    const float* __restrict__ Op, const int* __restrict__ slot_of,
    const float* __restrict__ t2w, float* __restrict__ out) {
  int t = blockIdx.x;
  int d4 = threadIdx.x << 2;
  int s0 = slot_of[2 * t], s1 = slot_of[2 * t + 1];
  float w0 = t2w[2 * t], w1 = t2w[2 * t + 1];
  float4 a = *(const float4*)&Op[(size_t)s0 * DMODEL + d4];
  float4 b = *(const float4*)&Op[(size_t)s1 * DMODEL + d4];
  float4 r;
  r.x = w0 * a.x + w1 * b.x;
  r.y = w0 * a.y + w1 * b.y;
  r.z = w0 * a.z + w1 * b.z;
  r.w = w0 * a.w + w1 * b.w;
  *(float4*)&out[(size_t)t * DMODEL + d4] = r;
}

// ================= fallback (R2-proven, fp32 direct) =================
__device__ __forceinline__ void wpack(u32* lds, int k2, int n8, uint4 a, uint4 b) {
  int idx = n8 * WSTR + k2;
  lds[idx + 0 * WSTR] = (a.x & 0xffffu) | (b.x << 16);
  lds[idx + 1 * WSTR] = (a.x >> 16) | (b.x & 0xffff0000u);
  lds[idx + 2 * WSTR] = (a.y & 0xffffu) | (b.y << 16);
  lds[idx + 3 * WSTR] = (a.y >> 16) | (b.y & 0xffff0000u);
  lds[idx + 4 * WSTR] = (a.z & 0xffffu) | (b.z << 16);
  lds[idx + 5 * WSTR] = (a.z >> 16) | (b.z & 0xffff0000u);
  lds[idx + 6 * WSTR] = (a.w & 0xffffu) | (b.w << 16);
  lds[idx + 7 * WSTR] = (a.w >> 16) | (b.w & 0xffff0000u);
}

__global__ __launch_bounds__(256) void k_stage1f(
    const float* __restrict__ xv, const float* __restrict__ wgv, const float* __restrict__ wuv,
    const int* __restrict__ meta, const int* __restrict__ tok, u16* __restrict__ H) {
  __shared__ u16 Xs[64 * 32];
  __shared__ u16 Wgs[128 * BKP];
  __shared__ u16 Wus[128 * BKP];
  int e = blockIdx.z;
  int off_e = meta[M_OFF + e];
  int rows_e = meta[M_OFF + e + 1] - off_e;
  int r0 = blockIdx.y * 64;
  if (r0 >= rows_e) return;
  int rows_t = rows_e - r0; if (rows_t > 64) rows_t = 64;
  int f0 = blockIdx.x * 128;
  int tid = threadIdx.x, lane = tid & 63, w = tid >> 6;
  int wr = w >> 1, wc = w & 1;
  int srow = (w << 4) + (lane >> 2);
  int trow = (srow < rows_t) ? tok[off_e + r0 + srow] : tok[off_e];
  int xcol = (lane & 3) << 3;
  u16* xl = &Xs[srow * 32 + xcol];
  int k2 = tid >> 4, n8 = (tid & 15) << 3;
  size_t wbase = (size_t)e * (DMODEL * DFF) + (size_t)(k2 << 1) * DFF + f0 + n8;
  f32x4 accg[2][4], accu[2][4];
#pragma unroll
  for (int i = 0; i < 2; ++i)
#pragma unroll
    for (int j = 0; j < 4; ++j) {
      accg[i][j] = (f32x4){0.f, 0.f, 0.f, 0.f};
      accu[i][j] = (f32x4){0.f, 0.f, 0.f, 0.f};
    }
  for (int kk = 0; kk < DMODEL / 32; ++kk) {
    int k0 = kk << 5;
    const float* xg = xv + (size_t)trow * DMODEL + xcol;
    const float* wgp = wgv + wbase;
    const float* wup = wuv + wbase;
    uint4 xa = cvt8(*(const float4*)(xg + k0), *(const float4*)(xg + k0 + 4));
    uint4 ga = cvt8(*(const float4*)(wgp + (size_t)k0 * DFF), *(const float4*)(wgp + (size_t)k0 * DFF + 4));
    uint4 gb = cvt8(*(const float4*)(wgp + (size_t)k0 * DFF + DFF), *(const float4*)(wgp + (size_t)k0 * DFF + DFF + 4));
    uint4 ua = cvt8(*(const float4*)(wup + (size_t)k0 * DFF), *(const float4*)(wup + (size_t)k0 * DFF + 4));
    uint4 ub = cvt8(*(const float4*)(wup + (size_t)k0 * DFF + DFF), *(const float4*)(wup + (size_t)k0 * DFF + DFF + 4));
    __syncthreads();
    *(uint4*)xl = xa;
    wpack((u32*)Wgs, k2, n8, ga, gb);
    wpack((u32*)Wus, k2, n8, ua, ub);
    __syncthreads();
    short8 af[2];
#pragma unroll
    for (int mt = 0; mt < 2; ++mt)
      af[mt] = *(const short8*)&Xs[((wr << 5) + (mt << 4) + (lane & 15)) * 32 + ((lane >> 4) << 3)];
#pragma unroll
    for (int nt = 0; nt < 4; ++nt) {
      int col = (wc << 6) + (nt << 4) + (lane & 15);
      short8 bg = *(const short8*)&Wgs[col * BKP + ((lane >> 4) << 3)];
      short8 bu = *(const short8*)&Wus[col * BKP + ((lane >> 4) << 3)];
#pragma unroll
      for (int mt = 0; mt < 2; ++mt) {
        accg[mt][nt] = __builtin_amdgcn_mfma_f32_16x16x32_bf16(af[mt], bg, accg[mt][nt], 0, 0, 0);
        accu[mt][nt] = __builtin_amdgcn_mfma_f32_16x16x32_bf16(af[mt], bu, accu[mt][nt], 0, 0, 0);
      }
    }
  }
  int q = lane >> 4, c = lane & 15;
#pragma unroll
  for (int mt = 0; mt < 2; ++mt)
#pragma unroll
    for (int r = 0; r < 4; ++r) {
      int lrow = (wr << 5) + (mt << 4) + (q << 2) + r;
      if (lrow < rows_t) {
        size_t rowbase = (size_t)(off_e + r0 + lrow) * DFF + f0 + (wc << 6);
#pragma unroll
        for (int nt = 0; nt < 4; ++nt) {
          float g = accg[mt][nt][r], u = accu[mt][nt][r];
          float h = g / (1.f + __expf(-g)) * u;
          H[rowbase + (nt << 4) + c] = f2b(h);
        }
      }
    }
}

__global__ __launch_bounds__(256) void k_stage2f(
    const u16* __restrict__ H, const float* __restrict__ wdv,
    const int* __restrict__ meta, float* __restrict__ Op) {
  __shared__ u16 As[64 * 32];
  __shared__ u16 Ws[128 * BKP];
  int e = blockIdx.z;
  int off_e = meta[M_OFF + e];
  int rows_e = meta[M_OFF + e + 1] - off_e;
  int r0 = blockIdx.y * 64;
  if (r0 >= rows_e) return;
  int rows_t = rows_e - r0; if (rows_t > 64) rows_t = 64;
  int n0 = blockIdx.x * 128;
  int tid = threadIdx.x, lane = tid & 63, w = tid >> 6;
  int wr = w >> 1, wc = w & 1;
  int srow = (w << 4) + (lane >> 2);
  int hrow = off_e + r0 + ((srow < rows_t) ? srow : 0);
  const u16* ag = H + (size_t)hrow * DFF + ((lane & 3) << 3);
  u16* al = &As[srow * 32 + ((lane & 3) << 3)];
  int k2 = tid >> 4, n8 = (tid & 15) << 3;
  size_t wbase = (size_t)e * (DFF * DMODEL) + (size_t)(k2 << 1) * DMODEL + n0 + n8;
  f32x4 acc[2][4];
#pragma unroll
  for (int i = 0; i < 2; ++i)
#pragma unroll
    for (int j = 0; j < 4; ++j) acc[i][j] = (f32x4){0.f, 0.f, 0.f, 0.f};
  for (int kk = 0; kk < DFF / 32; ++kk) {
    int k0 = kk << 5;
    uint4 xa = *(const uint4*)(ag + k0);
    const float* wdp = wdv + wbase;
    uint4 ga = cvt8(*(const float4*)(wdp + (size_t)k0 * DMODEL), *(const float4*)(wdp + (size_t)k0 * DMODEL + 4));
    uint4 gb = cvt8(*(const float4*)(wdp + (size_t)k0 * DMODEL + DMODEL), *(const float4*)(wdp + (size_t)k0 * DMODEL + DMODEL + 4));
    __syncthreads();
    *(uint4*)al = xa;
    wpack((u32*)Ws, k2, n8, ga, gb);
    __syncthreads();
    short8 af[2];
#pragma unroll
    for (int mt = 0; mt < 2; ++mt)
      af[mt] = *(const short8*)&As[((wr << 5) + (mt << 4) + (lane & 15)) * 32 + ((lane >> 4) << 3)];
#pragma unroll
    for (int nt = 0; nt < 4; ++nt) {
      int col = (wc << 6) + (nt << 4) + (lane & 15);
      short8 b = *(const short8*)&Ws[col * BKP + ((lane >> 4) << 3)];
#pragma unroll
      for (int mt = 0; mt < 2; ++mt)
        acc[mt][nt] = __builtin_amdgcn_mfma_f32_16x16x32_bf16(af[mt], b, acc[mt][nt], 0, 0, 0);
    }
  }
  int q = lane >> 4, c = lane & 15;
#pragma unroll
  for (int mt = 0; mt < 2; ++mt)
#pragma unroll
    for (int r = 0; r < 4; ++r) {
      int lrow = (wr << 5) + (mt << 4) + (q << 2) + r;
      if (lrow < rows_t) {
        size_t rowbase = (size_t)(off_e + r0 + lrow) * DMODEL + n0 + (wc << 6);
#pragma unroll
        for (int nt = 0; nt < 4; ++nt)
          Op[rowbase + (nt << 4) + c] = acc[mt][nt][r];
      }
    }
}

extern "C" void kernel_launch(void* const* d_in, const int* in_sizes, int n_in,
                              void* d_out, int out_size, void* d_ws, size_t ws_size,
                              hipStream_t stream) {
  const float* x  = (const float*)d_in[0];
  const float* gw = (const float*)d_in[1];
  const float* wg = (const float*)d_in[2];
  const float* wu = (const float*)d_in[3];
  const float* wd = (const float*)d_in[4];
  float* out = (float*)d_out;

  char* ws = (char*)d_ws;
  int* meta = (int*)ws;
  int* t2e        = (int*)(ws + 256);
  int* slot_of    = (int*)(ws + 16640);
  int* tok_of_row = (int*)(ws + 33024);
  float* t2w      = (float*)(ws + 49408);
  u16* Xb         = (u16*)(ws + 65792);                 // [2048*768] bf16

  k_init<<<1, 64, 0, stream>>>(meta);
  k_router<<<T_TOK / 4, 256, 0, stream>>>(x, gw, meta, t2e, t2w, Xb);
  k_scan<<<1, 64, 0, stream>>>(meta, out);
  k_scatter<<<T_TOK / 256, 256, 0, stream>>>(t2e, meta, tok_of_row, slot_of);

  const size_t NEED = 108069120;  // fast-path ws footprint
  if (ws_size >= NEED) {
    u16* H     = (u16*)(ws + 3211520);               // [4096*2048] bf16
    float* Op  = (float*)(ws + 19988736);            // [4096*768] fp32
    u16* WgB   = (u16*)(ws + 32571648);              // blocked bf16
    u16* WuB   = (u16*)(ws + 57737472);
    u16* WdB   = (u16*)(ws + 82903296);

    dim3 tg1(DFF / 128, DMODEL / 32, NEXP);   // (16,24,8)
    k_wtrans<<<tg1, 256, 0, stream>>>(wg, WgB, DMODEL, DFF);
    k_wtrans<<<tg1, 256, 0, stream>>>(wu, WuB, DMODEL, DFF);
    dim3 tg2(DMODEL / 128, DFF / 32, NEXP);   // (6,64,8)
    k_wtrans<<<tg2, 256, 0, stream>>>(wd, WdB, DFF, DMODEL);

    dim3 g1(16, 16, NEXP);
    k_stage1b<<<g1, 256, 0, stream>>>(Xb, WgB, WuB, meta, tok_of_row, H);
    dim3 g2(16, 6, NEXP);
    k_stage2b<<<g2, 256, 0, stream>>>(H, WdB, meta, Op);
    k_combine<<<T_TOK, 192, 0, stream>>>(Op, slot_of, t2w, out);
  } else {
    u16* H    = (u16*)(ws + 65792);
    float* Op = (float*)(ws + 65792 + 16777216);
    dim3 g1(DFF / 128, T_TOK / 64, NEXP);
    k_stage1f<<<g1, 256, 0, stream>>>(x, wg, wu, meta, tok_of_row, H);
    dim3 g2(DMODEL / 128, T_TOK / 64, NEXP);
    k_stage2f<<<g2, 256, 0, stream>>>(H, wd, meta, Op);
    k_combine<<<T_TOK, 192, 0, stream>>>(Op, slot_of, t2w, out);
  }
}